// Round 2
// baseline (1091.578 us; speedup 1.0000x reference)
//
#include <hip/hip_runtime.h>
#include <math.h>

constexpr float NEG_SLOPE = 0.2f;
constexpr float BN_EPS_C = 1e-5f;

// ---------------- CSR build ----------------

__global__ void count_kernel(const int* __restrict__ ei, int* __restrict__ counts,
                             int E, int N) {
    int i = blockIdx.x * blockDim.x + threadIdx.x;
    int ET = E + N;
    if (i >= ET) return;
    int d = (i < E) ? ei[E + i] : (i - E);
    atomicAdd(&counts[d], 1);
}

__global__ void scan_kernel(const int* __restrict__ counts, int* __restrict__ row_ptr, int n) {
    __shared__ int partial[1024];
    int t = threadIdx.x;
    int CH = (n + 1023) >> 10;
    int beg = t * CH;
    int end = min(beg + CH, n);
    int s = 0;
    for (int i = beg; i < end; ++i) s += counts[i];
    partial[t] = s;
    __syncthreads();
    for (int off = 1; off < 1024; off <<= 1) {
        int v = (t >= off) ? partial[t - off] : 0;
        __syncthreads();
        partial[t] += v;
        __syncthreads();
    }
    int prefix = (t == 0) ? 0 : partial[t - 1];
    for (int i = beg; i < end; ++i) {
        row_ptr[i] = prefix;
        prefix += counts[i];
    }
    if (t == 1023) row_ptr[n] = prefix;
}

__global__ void scatter_kernel(const int* __restrict__ ei, const int* __restrict__ row_ptr,
                               int* __restrict__ cursor, int* __restrict__ srcs, int E, int N) {
    int i = blockIdx.x * blockDim.x + threadIdx.x;
    int ET = E + N;
    if (i >= ET) return;
    int s, d;
    if (i < E) { s = ei[i]; d = ei[E + i]; }
    else       { s = i - E; d = s; }
    int pos = row_ptr[d] + atomicAdd(&cursor[d], 1);
    srcs[pos] = s;
}

// ---------------- fused GEMM (h = X @ W^T) + attention alphas ----------------
// Two-stage K loop: LDS = Xs[64][68] + Ws[JP][68] -> 52 KB (FOUT=128) => 3 blocks/CU.

template<int FOUT, int H>
__global__ __launch_bounds__(256)
void gemm_alpha_kernel(const float* __restrict__ X, const float* __restrict__ W,
                       const float* __restrict__ a_src, const float* __restrict__ a_dst,
                       float* __restrict__ h, float* __restrict__ asrc, float* __restrict__ adst,
                       int N) {
    constexpr int NJ = (FOUT + 15) / 16;
    constexpr int JP = NJ * 16;
    __shared__ float Xs[64][68];
    __shared__ float Ws[JP][68];
    const int t = threadIdx.x;
    const int n0 = blockIdx.x * 64;

    const int tr = t >> 4;   // 16 row-groups of 4 nodes
    const int tc = t & 15;   // 16 col threads; thread covers j = tc + jj*16
    float acc[4][NJ];
#pragma unroll
    for (int i = 0; i < 4; ++i)
#pragma unroll
        for (int jj = 0; jj < NJ; ++jj) acc[i][jj] = 0.f;

    for (int kh = 0; kh < 2; ++kh) {
        // stage X half-tile: 64 rows x 16 float4
#pragma unroll
        for (int i = 0; i < 4; ++i) {
            int lin = t + i * 256;
            int r = lin >> 4;
            int kq = (lin & 15) << 2;
            int gn = n0 + r;
            float4 v = make_float4(0.f, 0.f, 0.f, 0.f);
            if (gn < N) v = *reinterpret_cast<const float4*>(&X[(size_t)gn * 128 + kh * 64 + kq]);
            *reinterpret_cast<float4*>(&Xs[r][kq]) = v;
        }
        // stage W half-tile: JP rows x 16 float4
        constexpr int WITERS = (JP * 16 + 255) / 256;
#pragma unroll
        for (int i = 0; i < WITERS; ++i) {
            int lin = t + i * 256;
            if (lin < JP * 16) {
                int j = lin >> 4;
                int kq = (lin & 15) << 2;
                float4 v = make_float4(0.f, 0.f, 0.f, 0.f);
                if (j < FOUT) v = *reinterpret_cast<const float4*>(&W[(size_t)j * 128 + kh * 64 + kq]);
                *reinterpret_cast<float4*>(&Ws[j][kq]) = v;
            }
        }
        __syncthreads();

        for (int k = 0; k < 64; k += 4) {
            float4 xv[4];
#pragma unroll
            for (int i = 0; i < 4; ++i)
                xv[i] = *reinterpret_cast<const float4*>(&Xs[tr * 4 + i][k]);
            float4 wv[NJ];
#pragma unroll
            for (int jj = 0; jj < NJ; ++jj)
                wv[jj] = *reinterpret_cast<const float4*>(&Ws[tc + jj * 16][k]);
#pragma unroll
            for (int i = 0; i < 4; ++i)
#pragma unroll
                for (int jj = 0; jj < NJ; ++jj) {
                    acc[i][jj] += xv[i].x * wv[jj].x;
                    acc[i][jj] += xv[i].y * wv[jj].y;
                    acc[i][jj] += xv[i].z * wv[jj].z;
                    acc[i][jj] += xv[i].w * wv[jj].w;
                }
        }
        __syncthreads();
    }

#pragma unroll
    for (int i = 0; i < 4; ++i) {
        int gn = n0 + tr * 4 + i;
        bool ok = gn < N;
        float ps = 0.f, pd = 0.f;
#pragma unroll
        for (int jj = 0; jj < NJ; ++jj) {
            int j = tc + jj * 16;
            float v = acc[i][jj];
            bool jok = (j < FOUT);
            if (ok && jok) h[(size_t)gn * FOUT + j] = v;
            float av = jok ? a_src[j] : 0.f;
            float bv = jok ? a_dst[j] : 0.f;
            if constexpr (H == 8) {
                float p = v * av;
                float q = v * bv;
#pragma unroll
                for (int off = 1; off < 16; off <<= 1) {
                    p += __shfl_xor(p, off, 16);
                    q += __shfl_xor(q, off, 16);
                }
                if (tc == 0 && ok) {
                    asrc[(size_t)gn * 8 + jj] = p;
                    adst[(size_t)gn * 8 + jj] = q;
                }
            } else {
                ps += v * av;
                pd += v * bv;
            }
        }
        if constexpr (H == 1) {
#pragma unroll
            for (int off = 1; off < 16; off <<= 1) {
                ps += __shfl_xor(ps, off, 16);
                pd += __shfl_xor(pd, off, 16);
            }
            if (tc == 0 && ok) { asrc[gn] = ps; adst[gn] = pd; }
        }
    }
}

// ---------------- segment max + sum (softmax stats) ----------------

template<int H>
__global__ void maxsum_kernel(const int* __restrict__ row_ptr, const int* __restrict__ srcs,
                              const float* __restrict__ asrc, const float* __restrict__ adst,
                              float* __restrict__ emax, float* __restrict__ invden, int N) {
    int t = blockIdx.x * blockDim.x + threadIdx.x;
    int node = t / H;
    int hd = t - node * H;
    if (node >= N) return;
    int beg = row_ptr[node], end = row_ptr[node + 1];
    float ad = adst[(size_t)node * H + hd];
    float m = -1e30f;
    for (int j = beg; j < end; ++j) {
        int s = srcs[j];
        float e = asrc[(size_t)s * H + hd] + ad;
        e = (e > 0.f) ? e : NEG_SLOPE * e;
        m = fmaxf(m, e);
    }
    float sum = 0.f;
    for (int j = beg; j < end; ++j) {
        int s = srcs[j];
        float e = asrc[(size_t)s * H + hd] + ad;
        e = (e > 0.f) ? e : NEG_SLOPE * e;
        sum += __expf(e - m);
    }
    emax[(size_t)node * H + hd] = m;
    invden[(size_t)node * H + hd] = 1.0f / (sum + 1e-16f);
}

// ---------------- message aggregation, F=128, H=8, float4 gather ----------------
// 32 threads per node (4 channels each), 8 nodes per 256-thread block.

__global__ __launch_bounds__(256)
void message128_kernel(const float4* __restrict__ h4, const int* __restrict__ row_ptr,
                       const int* __restrict__ srcs,
                       const float* __restrict__ asrc, const float* __restrict__ adst,
                       const float* __restrict__ emax, const float* __restrict__ invden,
                       const float* __restrict__ bias,
                       const float* __restrict__ bn_g, const float* __restrict__ bn_b,
                       const float* __restrict__ bn_m, const float* __restrict__ bn_v,
                       float* __restrict__ out, int N) {
    int node = blockIdx.x * 8 + (threadIdx.x >> 5);
    if (node >= N) return;
    int tc = threadIdx.x & 31;      // float4 slot: channels [tc*4, tc*4+4)
    int hd = tc >> 2;
    int beg = row_ptr[node], end = row_ptr[node + 1];
    float ad = adst[(size_t)node * 8 + hd];
    float mx = emax[(size_t)node * 8 + hd];
    float inv = invden[(size_t)node * 8 + hd];
    float4 acc = make_float4(0.f, 0.f, 0.f, 0.f);
    int j = beg;
    for (; j + 2 <= end; j += 2) {
        int s0 = srcs[j];
        int s1 = srcs[j + 1];
        float4 v0 = h4[(size_t)s0 * 32 + tc];
        float4 v1 = h4[(size_t)s1 * 32 + tc];
        float e0 = asrc[(size_t)s0 * 8 + hd] + ad;
        float e1 = asrc[(size_t)s1 * 8 + hd] + ad;
        e0 = (e0 > 0.f) ? e0 : NEG_SLOPE * e0;
        e1 = (e1 > 0.f) ? e1 : NEG_SLOPE * e1;
        float w0 = __expf(e0 - mx) * inv;
        float w1 = __expf(e1 - mx) * inv;
        acc.x += w0 * v0.x; acc.y += w0 * v0.y; acc.z += w0 * v0.z; acc.w += w0 * v0.w;
        acc.x += w1 * v1.x; acc.y += w1 * v1.y; acc.z += w1 * v1.z; acc.w += w1 * v1.w;
    }
    if (j < end) {
        int s0 = srcs[j];
        float4 v0 = h4[(size_t)s0 * 32 + tc];
        float e0 = asrc[(size_t)s0 * 8 + hd] + ad;
        e0 = (e0 > 0.f) ? e0 : NEG_SLOPE * e0;
        float w0 = __expf(e0 - mx) * inv;
        acc.x += w0 * v0.x; acc.y += w0 * v0.y; acc.z += w0 * v0.z; acc.w += w0 * v0.w;
    }
    int c = tc * 4;
    float4 bi = *reinterpret_cast<const float4*>(&bias[c]);
    float4 g  = *reinterpret_cast<const float4*>(&bn_g[c]);
    float4 bb = *reinterpret_cast<const float4*>(&bn_b[c]);
    float4 mm = *reinterpret_cast<const float4*>(&bn_m[c]);
    float4 vv = *reinterpret_cast<const float4*>(&bn_v[c]);
    float r[4];
    r[0] = (acc.x + bi.x - mm.x) * rsqrtf(vv.x + BN_EPS_C) * g.x + bb.x;
    r[1] = (acc.y + bi.y - mm.y) * rsqrtf(vv.y + BN_EPS_C) * g.y + bb.y;
    r[2] = (acc.z + bi.z - mm.z) * rsqrtf(vv.z + BN_EPS_C) * g.z + bb.z;
    r[3] = (acc.w + bi.w - mm.w) * rsqrtf(vv.w + BN_EPS_C) * g.w + bb.w;
#pragma unroll
    for (int q = 0; q < 4; ++q) r[q] = (r[q] > 0.f) ? r[q] : expm1f(r[q]);
    *reinterpret_cast<float4*>(&out[(size_t)node * 128 + c]) =
        make_float4(r[0], r[1], r[2], r[3]);
}

// ---------------- message aggregation, F=40, H=1, float4 gather ----------------
// 16 threads per node (lanes 0..9 active for 10 float4 slots), 16 nodes/block.

__global__ __launch_bounds__(256)
void message40_kernel(const float4* __restrict__ h4, const int* __restrict__ row_ptr,
                      const int* __restrict__ srcs,
                      const float* __restrict__ asrc, const float* __restrict__ adst,
                      const float* __restrict__ emax, const float* __restrict__ invden,
                      const float* __restrict__ b2, float* __restrict__ out, int N) {
    int node = blockIdx.x * 16 + (threadIdx.x >> 4);
    if (node >= N) return;
    int tc = threadIdx.x & 15;
    int beg = row_ptr[node], end = row_ptr[node + 1];
    float ad = adst[node];
    float mx = emax[node];
    float inv = invden[node];
    float4 acc = make_float4(0.f, 0.f, 0.f, 0.f);
    int j = beg;
    for (; j + 2 <= end; j += 2) {
        int s0 = srcs[j];
        int s1 = srcs[j + 1];
        float4 v0 = make_float4(0.f, 0.f, 0.f, 0.f);
        float4 v1 = make_float4(0.f, 0.f, 0.f, 0.f);
        if (tc < 10) {
            v0 = h4[(size_t)s0 * 10 + tc];
            v1 = h4[(size_t)s1 * 10 + tc];
        }
        float e0 = asrc[s0] + ad;
        float e1 = asrc[s1] + ad;
        e0 = (e0 > 0.f) ? e0 : NEG_SLOPE * e0;
        e1 = (e1 > 0.f) ? e1 : NEG_SLOPE * e1;
        float w0 = __expf(e0 - mx) * inv;
        float w1 = __expf(e1 - mx) * inv;
        acc.x += w0 * v0.x; acc.y += w0 * v0.y; acc.z += w0 * v0.z; acc.w += w0 * v0.w;
        acc.x += w1 * v1.x; acc.y += w1 * v1.y; acc.z += w1 * v1.z; acc.w += w1 * v1.w;
    }
    if (j < end) {
        int s0 = srcs[j];
        float4 v0 = make_float4(0.f, 0.f, 0.f, 0.f);
        if (tc < 10) v0 = h4[(size_t)s0 * 10 + tc];
        float e0 = asrc[s0] + ad;
        e0 = (e0 > 0.f) ? e0 : NEG_SLOPE * e0;
        float w0 = __expf(e0 - mx) * inv;
        acc.x += w0 * v0.x; acc.y += w0 * v0.y; acc.z += w0 * v0.z; acc.w += w0 * v0.w;
    }
    if (tc < 10) {
        int c = tc * 4;
        float4 bi = *reinterpret_cast<const float4*>(&b2[c]);
        *reinterpret_cast<float4*>(&out[(size_t)node * 40 + c]) =
            make_float4(acc.x + bi.x, acc.y + bi.y, acc.z + bi.z, acc.w + bi.w);
    }
}

// ---------------- launcher ----------------

extern "C" void kernel_launch(void* const* d_in, const int* in_sizes, int n_in,
                              void* d_out, int out_size, void* d_ws, size_t ws_size,
                              hipStream_t stream) {
    const float* x   = (const float*)d_in[0];
    const int*   ei  = (const int*)d_in[1];
    const float* W0  = (const float*)d_in[2];
    const float* as0 = (const float*)d_in[3];
    const float* ad0 = (const float*)d_in[4];
    const float* b0  = (const float*)d_in[5];
    const float* g0  = (const float*)d_in[6];
    const float* bb0 = (const float*)d_in[7];
    const float* m0  = (const float*)d_in[8];
    const float* v0  = (const float*)d_in[9];
    const float* W1  = (const float*)d_in[10];
    const float* as1 = (const float*)d_in[11];
    const float* ad1 = (const float*)d_in[12];
    const float* b1  = (const float*)d_in[13];
    const float* g1  = (const float*)d_in[14];
    const float* bb1 = (const float*)d_in[15];
    const float* m1  = (const float*)d_in[16];
    const float* v1  = (const float*)d_in[17];
    const float* W2  = (const float*)d_in[18];
    const float* as2 = (const float*)d_in[19];
    const float* ad2 = (const float*)d_in[20];
    const float* b2  = (const float*)d_in[21];

    const int N  = in_sizes[0] / 128;
    const int E  = in_sizes[1] / 2;
    const int ET = E + N;

    char* wsp = (char*)d_ws;
    int* row_ptr = (int*)wsp;   wsp += (size_t)(N + 1) * 4;
    int* cursor  = (int*)wsp;   wsp += (size_t)N * 4 + 8;   // keep float4 alignment below
    int* srcs    = (int*)wsp;   wsp += (size_t)ET * 4;
    float* h     = (float*)wsp; wsp += (size_t)N * 128 * 4;
    float* feat  = (float*)wsp; wsp += (size_t)N * 128 * 4;
    float* asr   = (float*)wsp; wsp += (size_t)N * 8 * 4;
    float* adt   = (float*)wsp; wsp += (size_t)N * 8 * 4;
    float* emax  = (float*)wsp; wsp += (size_t)N * 8 * 4;
    float* invd  = (float*)wsp; wsp += (size_t)N * 8 * 4;

    // CSR build (once, reused by all 3 layers)
    hipMemsetAsync(cursor, 0, (size_t)N * 4, stream);
    count_kernel<<<(ET + 255) / 256, 256, 0, stream>>>(ei, cursor, E, N);
    scan_kernel<<<1, 1024, 0, stream>>>(cursor, row_ptr, N);
    hipMemsetAsync(cursor, 0, (size_t)N * 4, stream);
    scatter_kernel<<<(ET + 255) / 256, 256, 0, stream>>>(ei, row_ptr, cursor, srcs, E, N);

    const int gemm_grid = (N + 63) / 64;

    // layer 0: x -> feat
    gemm_alpha_kernel<128, 8><<<gemm_grid, 256, 0, stream>>>(x, W0, as0, ad0, h, asr, adt, N);
    maxsum_kernel<8><<<(N * 8 + 255) / 256, 256, 0, stream>>>(row_ptr, srcs, asr, adt, emax, invd, N);
    message128_kernel<<<(N + 7) / 8, 256, 0, stream>>>((const float4*)h, row_ptr, srcs, asr, adt,
                                                       emax, invd, b0, g0, bb0, m0, v0, feat, N);
    // layer 1: feat -> feat (reads h, safe in-place)
    gemm_alpha_kernel<128, 8><<<gemm_grid, 256, 0, stream>>>(feat, W1, as1, ad1, h, asr, adt, N);
    maxsum_kernel<8><<<(N * 8 + 255) / 256, 256, 0, stream>>>(row_ptr, srcs, asr, adt, emax, invd, N);
    message128_kernel<<<(N + 7) / 8, 256, 0, stream>>>((const float4*)h, row_ptr, srcs, asr, adt,
                                                       emax, invd, b1, g1, bb1, m1, v1, feat, N);
    // layer 2: feat -> d_out
    gemm_alpha_kernel<40, 1><<<gemm_grid, 256, 0, stream>>>(feat, W2, as2, ad2, h, asr, adt, N);
    maxsum_kernel<1><<<(N + 255) / 256, 256, 0, stream>>>(row_ptr, srcs, asr, adt, emax, invd, N);
    message40_kernel<<<(N + 15) / 16, 256, 0, stream>>>((const float4*)h, row_ptr, srcs, asr, adt,
                                                        emax, invd, b2, (float*)d_out, N);
}

// Round 3
// 505.376 us; speedup vs baseline: 2.1599x; 2.1599x over previous
//
#include <hip/hip_runtime.h>
#include <math.h>

constexpr float NEG_SLOPE = 0.2f;
constexpr float BN_EPS_C = 1e-5f;

// ---------------- CSR build ----------------

__global__ void count_kernel(const int* __restrict__ ei, int* __restrict__ counts,
                             int E, int N) {
    int i = blockIdx.x * blockDim.x + threadIdx.x;
    int ET = E + N;
    if (i >= ET) return;
    int d = (i < E) ? ei[E + i] : (i - E);
    atomicAdd(&counts[d], 1);
}

__global__ void scan_kernel(const int* __restrict__ counts, int* __restrict__ row_ptr, int n) {
    __shared__ int partial[1024];
    int t = threadIdx.x;
    int CH = (n + 1023) >> 10;
    int beg = t * CH;
    int end = min(beg + CH, n);
    int s = 0;
    for (int i = beg; i < end; ++i) s += counts[i];
    partial[t] = s;
    __syncthreads();
    for (int off = 1; off < 1024; off <<= 1) {
        int v = (t >= off) ? partial[t - off] : 0;
        __syncthreads();
        partial[t] += v;
        __syncthreads();
    }
    int prefix = (t == 0) ? 0 : partial[t - 1];
    for (int i = beg; i < end; ++i) {
        row_ptr[i] = prefix;
        prefix += counts[i];
    }
    if (t == 1023) row_ptr[n] = prefix;
}

__global__ void scatter_kernel(const int* __restrict__ ei, const int* __restrict__ row_ptr,
                               int* __restrict__ cursor, int* __restrict__ srcs, int E, int N) {
    int i = blockIdx.x * blockDim.x + threadIdx.x;
    int ET = E + N;
    if (i >= ET) return;
    int s, d;
    if (i < E) { s = ei[i]; d = ei[E + i]; }
    else       { s = i - E; d = s; }
    int pos = row_ptr[d] + atomicAdd(&cursor[d], 1);
    srcs[pos] = s;
}

// ---------------- GEMM 128: h = X @ W^T (+ per-head alphas) ----------------
// 256 threads = 8 row-threads x 32 col-threads. Thread: 8 node-rows x 4 cols.
// Xs[64][128] (reads are wave-broadcast), Wt[64][132] transposed K-half staging.
// LDS = 32 + 33.8 KB -> 2 blocks/CU. acc = 8 float4 = 32 VGPR.

__global__ __launch_bounds__(256)
void gemm128_alpha_kernel(const float* __restrict__ X, const float* __restrict__ W,
                          const float* __restrict__ a_src, const float* __restrict__ a_dst,
                          float* __restrict__ h, float* __restrict__ asrc,
                          float* __restrict__ adst, int N) {
    __shared__ float Xs[64][128];
    __shared__ float Wt[64][132];
    const int t = threadIdx.x;
    const int n0 = blockIdx.x * 64;
    const int tr = t >> 5;    // 0..7
    const int tc = t & 31;    // 0..31 ; cols 4*tc..4*tc+3

    // stage X tile (64x128), coalesced float4
#pragma unroll
    for (int i = 0; i < 8; ++i) {
        int lin = t + i * 256;
        int r = lin >> 5;
        int m = lin & 31;
        int gn = n0 + r;
        float4 v = make_float4(0.f, 0.f, 0.f, 0.f);
        if (gn < N) v = *reinterpret_cast<const float4*>(&X[(size_t)gn * 128 + 4 * m]);
        *reinterpret_cast<float4*>(&Xs[r][4 * m]) = v;
    }

    float4 acc[8];
#pragma unroll
    for (int i = 0; i < 8; ++i) acc[i] = make_float4(0.f, 0.f, 0.f, 0.f);

#pragma unroll 1
    for (int kh = 0; kh < 2; ++kh) {
        __syncthreads();   // Xs ready (kh=0) / previous Wt readers done (kh=1)
        // stage Wt[kl][j] = W[j][kh*64+kl]
#pragma unroll
        for (int i = 0; i < 8; ++i) {
            int lin = t + i * 256;
            int j = lin >> 4;
            int k4 = (lin & 15) << 2;
            float4 v = *reinterpret_cast<const float4*>(&W[(size_t)j * 128 + kh * 64 + k4]);
            Wt[k4 + 0][j] = v.x;
            Wt[k4 + 1][j] = v.y;
            Wt[k4 + 2][j] = v.z;
            Wt[k4 + 3][j] = v.w;
        }
        __syncthreads();

#pragma unroll 1
        for (int k0 = 0; k0 < 64; k0 += 4) {
            float4 wv0 = *reinterpret_cast<const float4*>(&Wt[k0 + 0][4 * tc]);
            float4 wv1 = *reinterpret_cast<const float4*>(&Wt[k0 + 1][4 * tc]);
            float4 wv2 = *reinterpret_cast<const float4*>(&Wt[k0 + 2][4 * tc]);
            float4 wv3 = *reinterpret_cast<const float4*>(&Wt[k0 + 3][4 * tc]);
#pragma unroll
            for (int i = 0; i < 8; ++i) {
                float4 xv = *reinterpret_cast<const float4*>(&Xs[tr + 8 * i][kh * 64 + k0 - kh * 64 + k0 * 0 + k0 - k0 + (kh * 64) + 0 - (kh * 64) + k0 * 0] + 0);
                // (simple form below; the above was getting silly)
                xv = *reinterpret_cast<const float4*>(&Xs[tr + 8 * i][kh * 64 + k0]);
                acc[i].x += xv.x * wv0.x; acc[i].y += xv.x * wv0.y;
                acc[i].z += xv.x * wv0.z; acc[i].w += xv.x * wv0.w;
                acc[i].x += xv.y * wv1.x; acc[i].y += xv.y * wv1.y;
                acc[i].z += xv.y * wv1.z; acc[i].w += xv.y * wv1.w;
                acc[i].x += xv.z * wv2.x; acc[i].y += xv.z * wv2.y;
                acc[i].z += xv.z * wv2.z; acc[i].w += xv.z * wv2.w;
                acc[i].x += xv.w * wv3.x; acc[i].y += xv.w * wv3.y;
                acc[i].z += xv.w * wv3.z; acc[i].w += xv.w * wv3.w;
            }
        }
    }

    // epilogue: write h + per-head alpha partials (4 lanes per head quad)
    const int hd = tc >> 2;
    float4 av = *reinterpret_cast<const float4*>(&a_src[4 * tc]);
    float4 bv = *reinterpret_cast<const float4*>(&a_dst[4 * tc]);
#pragma unroll
    for (int i = 0; i < 8; ++i) {
        int gn = n0 + tr + 8 * i;
        bool ok = gn < N;
        if (ok) *reinterpret_cast<float4*>(&h[(size_t)gn * 128 + 4 * tc]) = acc[i];
        float p = acc[i].x * av.x + acc[i].y * av.y + acc[i].z * av.z + acc[i].w * av.w;
        float q = acc[i].x * bv.x + acc[i].y * bv.y + acc[i].z * bv.z + acc[i].w * bv.w;
        p += __shfl_xor(p, 1, 4);
        p += __shfl_xor(p, 2, 4);
        q += __shfl_xor(q, 1, 4);
        q += __shfl_xor(q, 2, 4);
        if ((tc & 3) == 0 && ok) {
            asrc[(size_t)gn * 8 + hd] = p;
            adst[(size_t)gn * 8 + hd] = q;
        }
    }
}

// ---------------- GEMM 40: h2 = X @ W2^T (+ single-head alphas) ----------------
// 256 threads = 16 row-threads x 16 col-threads; thread: 4 rows x 3 cols (j=tc+16jj).
// Wt[128][48] transposed, cols 40..47 zeroed. LDS = 32 + 24.6 KB -> 2 blocks/CU.

__global__ __launch_bounds__(256)
void gemm40_alpha_kernel(const float* __restrict__ X, const float* __restrict__ W,
                         const float* __restrict__ a_src, const float* __restrict__ a_dst,
                         float* __restrict__ h, float* __restrict__ asrc,
                         float* __restrict__ adst, int N) {
    __shared__ float Xs[64][128];
    __shared__ float Wt[128][48];
    const int t = threadIdx.x;
    const int n0 = blockIdx.x * 64;
    const int tr = t >> 4;    // 0..15
    const int tc = t & 15;    // 0..15

#pragma unroll
    for (int i = 0; i < 8; ++i) {
        int lin = t + i * 256;
        int r = lin >> 5;
        int m = lin & 31;
        int gn = n0 + r;
        float4 v = make_float4(0.f, 0.f, 0.f, 0.f);
        if (gn < N) v = *reinterpret_cast<const float4*>(&X[(size_t)gn * 128 + 4 * m]);
        *reinterpret_cast<float4*>(&Xs[r][4 * m]) = v;
    }
    // stage Wt[k][j] = W[j][k]  (40 rows), j in 0..39
#pragma unroll
    for (int i = 0; i < 5; ++i) {
        int lin = t + i * 256;
        if (lin < 1280) {
            int j = lin >> 5;
            int k4 = (lin & 31) << 2;
            float4 v = *reinterpret_cast<const float4*>(&W[(size_t)j * 128 + k4]);
            Wt[k4 + 0][j] = v.x;
            Wt[k4 + 1][j] = v.y;
            Wt[k4 + 2][j] = v.z;
            Wt[k4 + 3][j] = v.w;
        }
    }
    // zero the pad cols 40..47
    for (int idx = t; idx < 128 * 8; idx += 256)
        Wt[idx >> 3][40 + (idx & 7)] = 0.f;
    __syncthreads();

    float acc[4][3];
#pragma unroll
    for (int i = 0; i < 4; ++i)
#pragma unroll
        for (int jj = 0; jj < 3; ++jj) acc[i][jj] = 0.f;

#pragma unroll 1
    for (int k0 = 0; k0 < 128; k0 += 4) {
        float4 xv[4];
#pragma unroll
        for (int i = 0; i < 4; ++i)
            xv[i] = *reinterpret_cast<const float4*>(&Xs[4 * tr + i][k0]);
#pragma unroll
        for (int q = 0; q < 4; ++q) {
            float w0 = Wt[k0 + q][tc];
            float w1 = Wt[k0 + q][tc + 16];
            float w2 = Wt[k0 + q][tc + 32];
#pragma unroll
            for (int i = 0; i < 4; ++i) {
                float xq = (q == 0) ? xv[i].x : (q == 1) ? xv[i].y : (q == 2) ? xv[i].z : xv[i].w;
                acc[i][0] += xq * w0;
                acc[i][1] += xq * w1;
                acc[i][2] += xq * w2;
            }
        }
    }

#pragma unroll
    for (int i = 0; i < 4; ++i) {
        int gn = n0 + 4 * tr + i;
        bool ok = gn < N;
        float ps = 0.f, pd = 0.f;
#pragma unroll
        for (int jj = 0; jj < 3; ++jj) {
            int j = tc + 16 * jj;
            bool jok = j < 40;
            float v = acc[i][jj];
            if (ok && jok) h[(size_t)gn * 40 + j] = v;
            ps += v * (jok ? a_src[j] : 0.f);
            pd += v * (jok ? a_dst[j] : 0.f);
        }
#pragma unroll
        for (int off = 1; off < 16; off <<= 1) {
            ps += __shfl_xor(ps, off, 16);
            pd += __shfl_xor(pd, off, 16);
        }
        if (tc == 0 && ok) { asrc[gn] = ps; adst[gn] = pd; }
    }
}

// ---------------- segment max + sum (softmax stats) ----------------

template<int H>
__global__ void maxsum_kernel(const int* __restrict__ row_ptr, const int* __restrict__ srcs,
                              const float* __restrict__ asrc, const float* __restrict__ adst,
                              float* __restrict__ emax, float* __restrict__ invden, int N) {
    int t = blockIdx.x * blockDim.x + threadIdx.x;
    int node = t / H;
    int hd = t - node * H;
    if (node >= N) return;
    int beg = row_ptr[node], end = row_ptr[node + 1];
    float ad = adst[(size_t)node * H + hd];
    float m = -1e30f;
    for (int j = beg; j < end; ++j) {
        int s = srcs[j];
        float e = asrc[(size_t)s * H + hd] + ad;
        e = (e > 0.f) ? e : NEG_SLOPE * e;
        m = fmaxf(m, e);
    }
    float sum = 0.f;
    for (int j = beg; j < end; ++j) {
        int s = srcs[j];
        float e = asrc[(size_t)s * H + hd] + ad;
        e = (e > 0.f) ? e : NEG_SLOPE * e;
        sum += __expf(e - m);
    }
    emax[(size_t)node * H + hd] = m;
    invden[(size_t)node * H + hd] = 1.0f / (sum + 1e-16f);
}

// ---------------- message aggregation, F=128, H=8, float4 gather ----------------

__global__ __launch_bounds__(256)
void message128_kernel(const float4* __restrict__ h4, const int* __restrict__ row_ptr,
                       const int* __restrict__ srcs,
                       const float* __restrict__ asrc, const float* __restrict__ adst,
                       const float* __restrict__ emax, const float* __restrict__ invden,
                       const float* __restrict__ bias,
                       const float* __restrict__ bn_g, const float* __restrict__ bn_b,
                       const float* __restrict__ bn_m, const float* __restrict__ bn_v,
                       float* __restrict__ out, int N) {
    int node = blockIdx.x * 8 + (threadIdx.x >> 5);
    if (node >= N) return;
    int tc = threadIdx.x & 31;
    int hd = tc >> 2;
    int beg = row_ptr[node], end = row_ptr[node + 1];
    float ad = adst[(size_t)node * 8 + hd];
    float mx = emax[(size_t)node * 8 + hd];
    float inv = invden[(size_t)node * 8 + hd];
    float4 acc = make_float4(0.f, 0.f, 0.f, 0.f);
    int j = beg;
    for (; j + 2 <= end; j += 2) {
        int s0 = srcs[j];
        int s1 = srcs[j + 1];
        float4 v0 = h4[(size_t)s0 * 32 + tc];
        float4 v1 = h4[(size_t)s1 * 32 + tc];
        float e0 = asrc[(size_t)s0 * 8 + hd] + ad;
        float e1 = asrc[(size_t)s1 * 8 + hd] + ad;
        e0 = (e0 > 0.f) ? e0 : NEG_SLOPE * e0;
        e1 = (e1 > 0.f) ? e1 : NEG_SLOPE * e1;
        float w0 = __expf(e0 - mx) * inv;
        float w1 = __expf(e1 - mx) * inv;
        acc.x += w0 * v0.x; acc.y += w0 * v0.y; acc.z += w0 * v0.z; acc.w += w0 * v0.w;
        acc.x += w1 * v1.x; acc.y += w1 * v1.y; acc.z += w1 * v1.z; acc.w += w1 * v1.w;
    }
    if (j < end) {
        int s0 = srcs[j];
        float4 v0 = h4[(size_t)s0 * 32 + tc];
        float e0 = asrc[(size_t)s0 * 8 + hd] + ad;
        e0 = (e0 > 0.f) ? e0 : NEG_SLOPE * e0;
        float w0 = __expf(e0 - mx) * inv;
        acc.x += w0 * v0.x; acc.y += w0 * v0.y; acc.z += w0 * v0.z; acc.w += w0 * v0.w;
    }
    int c = tc * 4;
    float4 bi = *reinterpret_cast<const float4*>(&bias[c]);
    float4 g  = *reinterpret_cast<const float4*>(&bn_g[c]);
    float4 bb = *reinterpret_cast<const float4*>(&bn_b[c]);
    float4 mm = *reinterpret_cast<const float4*>(&bn_m[c]);
    float4 vv = *reinterpret_cast<const float4*>(&bn_v[c]);
    float r[4];
    r[0] = (acc.x + bi.x - mm.x) * rsqrtf(vv.x + BN_EPS_C) * g.x + bb.x;
    r[1] = (acc.y + bi.y - mm.y) * rsqrtf(vv.y + BN_EPS_C) * g.y + bb.y;
    r[2] = (acc.z + bi.z - mm.z) * rsqrtf(vv.z + BN_EPS_C) * g.z + bb.z;
    r[3] = (acc.w + bi.w - mm.w) * rsqrtf(vv.w + BN_EPS_C) * g.w + bb.w;
#pragma unroll
    for (int q = 0; q < 4; ++q) r[q] = (r[q] > 0.f) ? r[q] : expm1f(r[q]);
    *reinterpret_cast<float4*>(&out[(size_t)node * 128 + c]) =
        make_float4(r[0], r[1], r[2], r[3]);
}

// ---------------- message aggregation, F=40, H=1 ----------------

__global__ __launch_bounds__(256)
void message40_kernel(const float4* __restrict__ h4, const int* __restrict__ row_ptr,
                      const int* __restrict__ srcs,
                      const float* __restrict__ asrc, const float* __restrict__ adst,
                      const float* __restrict__ emax, const float* __restrict__ invden,
                      const float* __restrict__ b2, float* __restrict__ out, int N) {
    int node = blockIdx.x * 16 + (threadIdx.x >> 4);
    if (node >= N) return;
    int tc = threadIdx.x & 15;
    int beg = row_ptr[node], end = row_ptr[node + 1];
    float ad = adst[node];
    float mx = emax[node];
    float inv = invden[node];
    float4 acc = make_float4(0.f, 0.f, 0.f, 0.f);
    int j = beg;
    for (; j + 2 <= end; j += 2) {
        int s0 = srcs[j];
        int s1 = srcs[j + 1];
        float4 v0 = make_float4(0.f, 0.f, 0.f, 0.f);
        float4 v1 = make_float4(0.f, 0.f, 0.f, 0.f);
        if (tc < 10) {
            v0 = h4[(size_t)s0 * 10 + tc];
            v1 = h4[(size_t)s1 * 10 + tc];
        }
        float e0 = asrc[s0] + ad;
        float e1 = asrc[s1] + ad;
        e0 = (e0 > 0.f) ? e0 : NEG_SLOPE * e0;
        e1 = (e1 > 0.f) ? e1 : NEG_SLOPE * e1;
        float w0 = __expf(e0 - mx) * inv;
        float w1 = __expf(e1 - mx) * inv;
        acc.x += w0 * v0.x; acc.y += w0 * v0.y; acc.z += w0 * v0.z; acc.w += w0 * v0.w;
        acc.x += w1 * v1.x; acc.y += w1 * v1.y; acc.z += w1 * v1.z; acc.w += w1 * v1.w;
    }
    if (j < end) {
        int s0 = srcs[j];
        float4 v0 = make_float4(0.f, 0.f, 0.f, 0.f);
        if (tc < 10) v0 = h4[(size_t)s0 * 10 + tc];
        float e0 = asrc[s0] + ad;
        e0 = (e0 > 0.f) ? e0 : NEG_SLOPE * e0;
        float w0 = __expf(e0 - mx) * inv;
        acc.x += w0 * v0.x; acc.y += w0 * v0.y; acc.z += w0 * v0.z; acc.w += w0 * v0.w;
    }
    if (tc < 10) {
        int c = tc * 4;
        float4 bi = *reinterpret_cast<const float4*>(&b2[c]);
        *reinterpret_cast<float4*>(&out[(size_t)node * 40 + c]) =
            make_float4(acc.x + bi.x, acc.y + bi.y, acc.z + bi.z, acc.w + bi.w);
    }
}

// ---------------- launcher ----------------

static inline char* align256(char* p) {
    return (char*)(((uintptr_t)p + 255) & ~(uintptr_t)255);
}

extern "C" void kernel_launch(void* const* d_in, const int* in_sizes, int n_in,
                              void* d_out, int out_size, void* d_ws, size_t ws_size,
                              hipStream_t stream) {
    const float* x   = (const float*)d_in[0];
    const int*   ei  = (const int*)d_in[1];
    const float* W0  = (const float*)d_in[2];
    const float* as0 = (const float*)d_in[3];
    const float* ad0 = (const float*)d_in[4];
    const float* b0  = (const float*)d_in[5];
    const float* g0  = (const float*)d_in[6];
    const float* bb0 = (const float*)d_in[7];
    const float* m0  = (const float*)d_in[8];
    const float* v0  = (const float*)d_in[9];
    const float* W1  = (const float*)d_in[10];
    const float* as1 = (const float*)d_in[11];
    const float* ad1 = (const float*)d_in[12];
    const float* b1  = (const float*)d_in[13];
    const float* g1  = (const float*)d_in[14];
    const float* bb1 = (const float*)d_in[15];
    const float* m1  = (const float*)d_in[16];
    const float* v1  = (const float*)d_in[17];
    const float* W2  = (const float*)d_in[18];
    const float* as2 = (const float*)d_in[19];
    const float* ad2 = (const float*)d_in[20];
    const float* b2  = (const float*)d_in[21];

    const int N  = in_sizes[0] / 128;
    const int E  = in_sizes[1] / 2;
    const int ET = E + N;

    char* wsp = (char*)d_ws;
    int* row_ptr = (int*)wsp;   wsp = align256(wsp + (size_t)(N + 1) * 4);
    int* cursor  = (int*)wsp;   wsp = align256(wsp + (size_t)N * 4);
    int* srcs    = (int*)wsp;   wsp = align256(wsp + (size_t)ET * 4);
    float* h     = (float*)wsp; wsp = align256(wsp + (size_t)N * 128 * 4);
    float* feat  = (float*)wsp; wsp = align256(wsp + (size_t)N * 128 * 4);
    float* asr   = (float*)wsp; wsp = align256(wsp + (size_t)N * 8 * 4);
    float* adt   = (float*)wsp; wsp = align256(wsp + (size_t)N * 8 * 4);
    float* emax  = (float*)wsp; wsp = align256(wsp + (size_t)N * 8 * 4);
    float* invd  = (float*)wsp; wsp = align256(wsp + (size_t)N * 8 * 4);

    // CSR build (once, reused by all 3 layers)
    hipMemsetAsync(cursor, 0, (size_t)N * 4, stream);
    count_kernel<<<(ET + 255) / 256, 256, 0, stream>>>(ei, cursor, E, N);
    scan_kernel<<<1, 1024, 0, stream>>>(cursor, row_ptr, N);
    hipMemsetAsync(cursor, 0, (size_t)N * 4, stream);
    scatter_kernel<<<(ET + 255) / 256, 256, 0, stream>>>(ei, row_ptr, cursor, srcs, E, N);

    const int gemm_grid = (N + 63) / 64;

    // layer 0: x -> feat
    gemm128_alpha_kernel<<<gemm_grid, 256, 0, stream>>>(x, W0, as0, ad0, h, asr, adt, N);
    maxsum_kernel<8><<<(N * 8 + 255) / 256, 256, 0, stream>>>(row_ptr, srcs, asr, adt, emax, invd, N);
    message128_kernel<<<(N + 7) / 8, 256, 0, stream>>>((const float4*)h, row_ptr, srcs, asr, adt,
                                                       emax, invd, b0, g0, bb0, m0, v0, feat, N);
    // layer 1: feat -> feat (reads h, safe in-place)
    gemm128_alpha_kernel<<<gemm_grid, 256, 0, stream>>>(feat, W1, as1, ad1, h, asr, adt, N);
    maxsum_kernel<8><<<(N * 8 + 255) / 256, 256, 0, stream>>>(row_ptr, srcs, asr, adt, emax, invd, N);
    message128_kernel<<<(N + 7) / 8, 256, 0, stream>>>((const float4*)h, row_ptr, srcs, asr, adt,
                                                       emax, invd, b1, g1, bb1, m1, v1, feat, N);
    // layer 2: feat -> d_out
    gemm40_alpha_kernel<<<gemm_grid, 256, 0, stream>>>(feat, W2, as2, ad2, h, asr, adt, N);
    maxsum_kernel<1><<<(N + 255) / 256, 256, 0, stream>>>(row_ptr, srcs, asr, adt, emax, invd, N);
    message40_kernel<<<(N + 15) / 16, 256, 0, stream>>>((const float4*)h, row_ptr, srcs, asr, adt,
                                                        emax, invd, b2, (float*)d_out, N);
}

// Round 4
// 437.610 us; speedup vs baseline: 2.4944x; 1.1549x over previous
//
#include <hip/hip_runtime.h>
#include <math.h>

constexpr float NEG_SLOPE = 0.2f;
constexpr float BN_EPS_C = 1e-5f;

// ---------------- CSR build ----------------

__global__ void count_kernel(const int* __restrict__ ei, int* __restrict__ counts,
                             int E, int N) {
    int i = blockIdx.x * blockDim.x + threadIdx.x;
    int ET = E + N;
    if (i >= ET) return;
    int d = (i < E) ? ei[E + i] : (i - E);
    atomicAdd(&counts[d], 1);
}

// Hierarchical scan: A) per-1024-chunk sums, B) scan chunk sums, C) local scan + write.

__global__ void block_sum_kernel(const int* __restrict__ counts, int* __restrict__ blocksums,
                                 int n) {
    __shared__ int sh[256];
    int b = blockIdx.x, t = threadIdx.x;
    int i0 = b * 1024 + t * 4;
    int s = 0;
#pragma unroll
    for (int q = 0; q < 4; ++q)
        if (i0 + q < n) s += counts[i0 + q];
    sh[t] = s;
    __syncthreads();
    for (int off = 128; off >= 1; off >>= 1) {
        if (t < off) sh[t] += sh[t + off];
        __syncthreads();
    }
    if (t == 0) blocksums[b] = sh[0];
}

__global__ void scan_sums_kernel(int* __restrict__ blocksums, int* __restrict__ row_ptr,
                                 int nb, int n) {
    __shared__ int sh[256];
    int t = threadIdx.x;
    int CH = (nb + 255) >> 8;
    int beg = t * CH, end = min(beg + CH, nb);
    int s = 0;
    for (int i = beg; i < end; ++i) s += blocksums[i];
    sh[t] = s;
    __syncthreads();
    for (int off = 1; off < 256; off <<= 1) {
        int v = (t >= off) ? sh[t - off] : 0;
        __syncthreads();
        sh[t] += v;
        __syncthreads();
    }
    int prefix = (t == 0) ? 0 : sh[t - 1];
    for (int i = beg; i < end; ++i) {
        int c = blocksums[i];
        blocksums[i] = prefix;   // becomes block prefix
        prefix += c;
    }
    if (t == 255) row_ptr[n] = sh[255];
}

__global__ void scan_write_kernel(const int* __restrict__ counts,
                                  const int* __restrict__ blockpref,
                                  int* __restrict__ row_ptr, int n) {
    __shared__ int sh[256];
    int b = blockIdx.x, t = threadIdx.x;
    int i0 = b * 1024 + t * 4;
    int c0 = (i0 + 0 < n) ? counts[i0 + 0] : 0;
    int c1 = (i0 + 1 < n) ? counts[i0 + 1] : 0;
    int c2 = (i0 + 2 < n) ? counts[i0 + 2] : 0;
    int c3 = (i0 + 3 < n) ? counts[i0 + 3] : 0;
    int ts = c0 + c1 + c2 + c3;
    sh[t] = ts;
    __syncthreads();
    for (int off = 1; off < 256; off <<= 1) {
        int v = (t >= off) ? sh[t - off] : 0;
        __syncthreads();
        sh[t] += v;
        __syncthreads();
    }
    int excl = ((t == 0) ? 0 : sh[t - 1]) + blockpref[b];
    if (i0 + 0 < n) row_ptr[i0 + 0] = excl;
    if (i0 + 1 < n) row_ptr[i0 + 1] = excl + c0;
    if (i0 + 2 < n) row_ptr[i0 + 2] = excl + c0 + c1;
    if (i0 + 3 < n) row_ptr[i0 + 3] = excl + c0 + c1 + c2;
}

__global__ void scatter_kernel(const int* __restrict__ ei, const int* __restrict__ row_ptr,
                               int* __restrict__ cursor, int* __restrict__ srcs, int E, int N) {
    int i = blockIdx.x * blockDim.x + threadIdx.x;
    int ET = E + N;
    if (i >= ET) return;
    int s, d;
    if (i < E) { s = ei[i]; d = ei[E + i]; }
    else       { s = i - E; d = s; }
    int pos = row_ptr[d] + atomicAdd(&cursor[d], 1);
    srcs[pos] = s;
}

// ---------------- GEMM 128: h = X @ W^T (+ per-head alphas) ----------------
// 256 threads = 8 row-threads x 32 col-threads. Thread: 8 node-rows x 4 cols.
// Xs[64][128] (reads are wave-broadcast), Wt[64][132] transposed K-half staging.
// LDS = 32 + 33.8 KB -> 2 blocks/CU. acc = 8 float4 = 32 VGPR.

__global__ __launch_bounds__(256)
void gemm128_alpha_kernel(const float* __restrict__ X, const float* __restrict__ W,
                          const float* __restrict__ a_src, const float* __restrict__ a_dst,
                          float* __restrict__ h, float* __restrict__ asrc,
                          float* __restrict__ adst, int N) {
    __shared__ float Xs[64][128];
    __shared__ float Wt[64][132];
    const int t = threadIdx.x;
    const int n0 = blockIdx.x * 64;
    const int tr = t >> 5;    // 0..7
    const int tc = t & 31;    // 0..31 ; cols 4*tc..4*tc+3

    // stage X tile (64x128), coalesced float4
#pragma unroll
    for (int i = 0; i < 8; ++i) {
        int lin = t + i * 256;
        int r = lin >> 5;
        int m = lin & 31;
        int gn = n0 + r;
        float4 v = make_float4(0.f, 0.f, 0.f, 0.f);
        if (gn < N) v = *reinterpret_cast<const float4*>(&X[(size_t)gn * 128 + 4 * m]);
        *reinterpret_cast<float4*>(&Xs[r][4 * m]) = v;
    }

    float4 acc[8];
#pragma unroll
    for (int i = 0; i < 8; ++i) acc[i] = make_float4(0.f, 0.f, 0.f, 0.f);

#pragma unroll 1
    for (int kh = 0; kh < 2; ++kh) {
        __syncthreads();   // Xs ready (kh=0) / previous Wt readers done (kh=1)
        // stage Wt[kl][j] = W[j][kh*64+kl]
#pragma unroll
        for (int i = 0; i < 8; ++i) {
            int lin = t + i * 256;
            int j = lin >> 4;
            int k4 = (lin & 15) << 2;
            float4 v = *reinterpret_cast<const float4*>(&W[(size_t)j * 128 + kh * 64 + k4]);
            Wt[k4 + 0][j] = v.x;
            Wt[k4 + 1][j] = v.y;
            Wt[k4 + 2][j] = v.z;
            Wt[k4 + 3][j] = v.w;
        }
        __syncthreads();

#pragma unroll 1
        for (int k0 = 0; k0 < 64; k0 += 4) {
            float4 wv0 = *reinterpret_cast<const float4*>(&Wt[k0 + 0][4 * tc]);
            float4 wv1 = *reinterpret_cast<const float4*>(&Wt[k0 + 1][4 * tc]);
            float4 wv2 = *reinterpret_cast<const float4*>(&Wt[k0 + 2][4 * tc]);
            float4 wv3 = *reinterpret_cast<const float4*>(&Wt[k0 + 3][4 * tc]);
#pragma unroll
            for (int i = 0; i < 8; ++i) {
                float4 xv = *reinterpret_cast<const float4*>(&Xs[tr + 8 * i][kh * 64 + k0]);
                acc[i].x += xv.x * wv0.x; acc[i].y += xv.x * wv0.y;
                acc[i].z += xv.x * wv0.z; acc[i].w += xv.x * wv0.w;
                acc[i].x += xv.y * wv1.x; acc[i].y += xv.y * wv1.y;
                acc[i].z += xv.y * wv1.z; acc[i].w += xv.y * wv1.w;
                acc[i].x += xv.z * wv2.x; acc[i].y += xv.z * wv2.y;
                acc[i].z += xv.z * wv2.z; acc[i].w += xv.z * wv2.w;
                acc[i].x += xv.w * wv3.x; acc[i].y += xv.w * wv3.y;
                acc[i].z += xv.w * wv3.z; acc[i].w += xv.w * wv3.w;
            }
        }
    }

    // epilogue: write h + per-head alpha partials (4 lanes per head quad)
    const int hd = tc >> 2;
    float4 av = *reinterpret_cast<const float4*>(&a_src[4 * tc]);
    float4 bv = *reinterpret_cast<const float4*>(&a_dst[4 * tc]);
#pragma unroll
    for (int i = 0; i < 8; ++i) {
        int gn = n0 + tr + 8 * i;
        bool ok = gn < N;
        if (ok) *reinterpret_cast<float4*>(&h[(size_t)gn * 128 + 4 * tc]) = acc[i];
        float p = acc[i].x * av.x + acc[i].y * av.y + acc[i].z * av.z + acc[i].w * av.w;
        float q = acc[i].x * bv.x + acc[i].y * bv.y + acc[i].z * bv.z + acc[i].w * bv.w;
        p += __shfl_xor(p, 1, 4);
        p += __shfl_xor(p, 2, 4);
        q += __shfl_xor(q, 1, 4);
        q += __shfl_xor(q, 2, 4);
        if ((tc & 3) == 0 && ok) {
            asrc[(size_t)gn * 8 + hd] = p;
            adst[(size_t)gn * 8 + hd] = q;
        }
    }
}

// ---------------- GEMM 40: h2 = X @ W2^T (+ single-head alphas) ----------------

__global__ __launch_bounds__(256)
void gemm40_alpha_kernel(const float* __restrict__ X, const float* __restrict__ W,
                         const float* __restrict__ a_src, const float* __restrict__ a_dst,
                         float* __restrict__ h, float* __restrict__ asrc,
                         float* __restrict__ adst, int N) {
    __shared__ float Xs[64][128];
    __shared__ float Wt[128][48];
    const int t = threadIdx.x;
    const int n0 = blockIdx.x * 64;
    const int tr = t >> 4;    // 0..15
    const int tc = t & 15;    // 0..15

#pragma unroll
    for (int i = 0; i < 8; ++i) {
        int lin = t + i * 256;
        int r = lin >> 5;
        int m = lin & 31;
        int gn = n0 + r;
        float4 v = make_float4(0.f, 0.f, 0.f, 0.f);
        if (gn < N) v = *reinterpret_cast<const float4*>(&X[(size_t)gn * 128 + 4 * m]);
        *reinterpret_cast<float4*>(&Xs[r][4 * m]) = v;
    }
    // stage Wt[k][j] = W[j][k]  (40 rows), j in 0..39
#pragma unroll
    for (int i = 0; i < 5; ++i) {
        int lin = t + i * 256;
        if (lin < 1280) {
            int j = lin >> 5;
            int k4 = (lin & 31) << 2;
            float4 v = *reinterpret_cast<const float4*>(&W[(size_t)j * 128 + k4]);
            Wt[k4 + 0][j] = v.x;
            Wt[k4 + 1][j] = v.y;
            Wt[k4 + 2][j] = v.z;
            Wt[k4 + 3][j] = v.w;
        }
    }
    // zero the pad cols 40..47
    for (int idx = t; idx < 128 * 8; idx += 256)
        Wt[idx >> 3][40 + (idx & 7)] = 0.f;
    __syncthreads();

    float acc[4][3];
#pragma unroll
    for (int i = 0; i < 4; ++i)
#pragma unroll
        for (int jj = 0; jj < 3; ++jj) acc[i][jj] = 0.f;

#pragma unroll 1
    for (int k0 = 0; k0 < 128; k0 += 4) {
        float4 xv[4];
#pragma unroll
        for (int i = 0; i < 4; ++i)
            xv[i] = *reinterpret_cast<const float4*>(&Xs[4 * tr + i][k0]);
#pragma unroll
        for (int q = 0; q < 4; ++q) {
            float w0 = Wt[k0 + q][tc];
            float w1 = Wt[k0 + q][tc + 16];
            float w2 = Wt[k0 + q][tc + 32];
#pragma unroll
            for (int i = 0; i < 4; ++i) {
                float xq = (q == 0) ? xv[i].x : (q == 1) ? xv[i].y : (q == 2) ? xv[i].z : xv[i].w;
                acc[i][0] += xq * w0;
                acc[i][1] += xq * w1;
                acc[i][2] += xq * w2;
            }
        }
    }

#pragma unroll
    for (int i = 0; i < 4; ++i) {
        int gn = n0 + 4 * tr + i;
        bool ok = gn < N;
        float ps = 0.f, pd = 0.f;
#pragma unroll
        for (int jj = 0; jj < 3; ++jj) {
            int j = tc + 16 * jj;
            bool jok = j < 40;
            float v = acc[i][jj];
            if (ok && jok) h[(size_t)gn * 40 + j] = v;
            ps += v * (jok ? a_src[j] : 0.f);
            pd += v * (jok ? a_dst[j] : 0.f);
        }
#pragma unroll
        for (int off = 1; off < 16; off <<= 1) {
            ps += __shfl_xor(ps, off, 16);
            pd += __shfl_xor(pd, off, 16);
        }
        if (tc == 0 && ok) { asrc[gn] = ps; adst[gn] = pd; }
    }
}

// ---------------- segment max + sum (softmax stats) ----------------

template<int H>
__global__ void maxsum_kernel(const int* __restrict__ row_ptr, const int* __restrict__ srcs,
                              const float* __restrict__ asrc, const float* __restrict__ adst,
                              float* __restrict__ emax, float* __restrict__ invden, int N) {
    int t = blockIdx.x * blockDim.x + threadIdx.x;
    int node = t / H;
    int hd = t - node * H;
    if (node >= N) return;
    int beg = row_ptr[node], end = row_ptr[node + 1];
    float ad = adst[(size_t)node * H + hd];
    float m = -1e30f;
    for (int j = beg; j < end; ++j) {
        int s = srcs[j];
        float e = asrc[(size_t)s * H + hd] + ad;
        e = (e > 0.f) ? e : NEG_SLOPE * e;
        m = fmaxf(m, e);
    }
    float sum = 0.f;
    for (int j = beg; j < end; ++j) {
        int s = srcs[j];
        float e = asrc[(size_t)s * H + hd] + ad;
        e = (e > 0.f) ? e : NEG_SLOPE * e;
        sum += __expf(e - m);
    }
    emax[(size_t)node * H + hd] = m;
    invden[(size_t)node * H + hd] = 1.0f / (sum + 1e-16f);
}

// ---------------- message aggregation, F=128, H=8, float4 gather ----------------

__global__ __launch_bounds__(256)
void message128_kernel(const float4* __restrict__ h4, const int* __restrict__ row_ptr,
                       const int* __restrict__ srcs,
                       const float* __restrict__ asrc, const float* __restrict__ adst,
                       const float* __restrict__ emax, const float* __restrict__ invden,
                       const float* __restrict__ bias,
                       const float* __restrict__ bn_g, const float* __restrict__ bn_b,
                       const float* __restrict__ bn_m, const float* __restrict__ bn_v,
                       float* __restrict__ out, int N) {
    int node = blockIdx.x * 8 + (threadIdx.x >> 5);
    if (node >= N) return;
    int tc = threadIdx.x & 31;
    int hd = tc >> 2;
    int beg = row_ptr[node], end = row_ptr[node + 1];
    float ad = adst[(size_t)node * 8 + hd];
    float mx = emax[(size_t)node * 8 + hd];
    float inv = invden[(size_t)node * 8 + hd];
    float4 acc = make_float4(0.f, 0.f, 0.f, 0.f);
    int j = beg;
    for (; j + 2 <= end; j += 2) {
        int s0 = srcs[j];
        int s1 = srcs[j + 1];
        float4 v0 = h4[(size_t)s0 * 32 + tc];
        float4 v1 = h4[(size_t)s1 * 32 + tc];
        float e0 = asrc[(size_t)s0 * 8 + hd] + ad;
        float e1 = asrc[(size_t)s1 * 8 + hd] + ad;
        e0 = (e0 > 0.f) ? e0 : NEG_SLOPE * e0;
        e1 = (e1 > 0.f) ? e1 : NEG_SLOPE * e1;
        float w0 = __expf(e0 - mx) * inv;
        float w1 = __expf(e1 - mx) * inv;
        acc.x += w0 * v0.x; acc.y += w0 * v0.y; acc.z += w0 * v0.z; acc.w += w0 * v0.w;
        acc.x += w1 * v1.x; acc.y += w1 * v1.y; acc.z += w1 * v1.z; acc.w += w1 * v1.w;
    }
    if (j < end) {
        int s0 = srcs[j];
        float4 v0 = h4[(size_t)s0 * 32 + tc];
        float e0 = asrc[(size_t)s0 * 8 + hd] + ad;
        e0 = (e0 > 0.f) ? e0 : NEG_SLOPE * e0;
        float w0 = __expf(e0 - mx) * inv;
        acc.x += w0 * v0.x; acc.y += w0 * v0.y; acc.z += w0 * v0.z; acc.w += w0 * v0.w;
    }
    int c = tc * 4;
    float4 bi = *reinterpret_cast<const float4*>(&bias[c]);
    float4 g  = *reinterpret_cast<const float4*>(&bn_g[c]);
    float4 bb = *reinterpret_cast<const float4*>(&bn_b[c]);
    float4 mm = *reinterpret_cast<const float4*>(&bn_m[c]);
    float4 vv = *reinterpret_cast<const float4*>(&bn_v[c]);
    float r[4];
    r[0] = (acc.x + bi.x - mm.x) * rsqrtf(vv.x + BN_EPS_C) * g.x + bb.x;
    r[1] = (acc.y + bi.y - mm.y) * rsqrtf(vv.y + BN_EPS_C) * g.y + bb.y;
    r[2] = (acc.z + bi.z - mm.z) * rsqrtf(vv.z + BN_EPS_C) * g.z + bb.z;
    r[3] = (acc.w + bi.w - mm.w) * rsqrtf(vv.w + BN_EPS_C) * g.w + bb.w;
#pragma unroll
    for (int q = 0; q < 4; ++q) r[q] = (r[q] > 0.f) ? r[q] : expm1f(r[q]);
    *reinterpret_cast<float4*>(&out[(size_t)node * 128 + c]) =
        make_float4(r[0], r[1], r[2], r[3]);
}

// ---------------- message aggregation, F=40, H=1 ----------------

__global__ __launch_bounds__(256)
void message40_kernel(const float4* __restrict__ h4, const int* __restrict__ row_ptr,
                      const int* __restrict__ srcs,
                      const float* __restrict__ asrc, const float* __restrict__ adst,
                      const float* __restrict__ emax, const float* __restrict__ invden,
                      const float* __restrict__ b2, float* __restrict__ out, int N) {
    int node = blockIdx.x * 16 + (threadIdx.x >> 4);
    if (node >= N) return;
    int tc = threadIdx.x & 15;
    int beg = row_ptr[node], end = row_ptr[node + 1];
    float ad = adst[node];
    float mx = emax[node];
    float inv = invden[node];
    float4 acc = make_float4(0.f, 0.f, 0.f, 0.f);
    int j = beg;
    for (; j + 2 <= end; j += 2) {
        int s0 = srcs[j];
        int s1 = srcs[j + 1];
        float4 v0 = make_float4(0.f, 0.f, 0.f, 0.f);
        float4 v1 = make_float4(0.f, 0.f, 0.f, 0.f);
        if (tc < 10) {
            v0 = h4[(size_t)s0 * 10 + tc];
            v1 = h4[(size_t)s1 * 10 + tc];
        }
        float e0 = asrc[s0] + ad;
        float e1 = asrc[s1] + ad;
        e0 = (e0 > 0.f) ? e0 : NEG_SLOPE * e0;
        e1 = (e1 > 0.f) ? e1 : NEG_SLOPE * e1;
        float w0 = __expf(e0 - mx) * inv;
        float w1 = __expf(e1 - mx) * inv;
        acc.x += w0 * v0.x; acc.y += w0 * v0.y; acc.z += w0 * v0.z; acc.w += w0 * v0.w;
        acc.x += w1 * v1.x; acc.y += w1 * v1.y; acc.z += w1 * v1.z; acc.w += w1 * v1.w;
    }
    if (j < end) {
        int s0 = srcs[j];
        float4 v0 = make_float4(0.f, 0.f, 0.f, 0.f);
        if (tc < 10) v0 = h4[(size_t)s0 * 10 + tc];
        float e0 = asrc[s0] + ad;
        e0 = (e0 > 0.f) ? e0 : NEG_SLOPE * e0;
        float w0 = __expf(e0 - mx) * inv;
        acc.x += w0 * v0.x; acc.y += w0 * v0.y; acc.z += w0 * v0.z; acc.w += w0 * v0.w;
    }
    if (tc < 10) {
        int c = tc * 4;
        float4 bi = *reinterpret_cast<const float4*>(&b2[c]);
        *reinterpret_cast<float4*>(&out[(size_t)node * 40 + c]) =
            make_float4(acc.x + bi.x, acc.y + bi.y, acc.z + bi.z, acc.w + bi.w);
    }
}

// ---------------- launcher ----------------

static inline char* align256(char* p) {
    return (char*)(((uintptr_t)p + 255) & ~(uintptr_t)255);
}

extern "C" void kernel_launch(void* const* d_in, const int* in_sizes, int n_in,
                              void* d_out, int out_size, void* d_ws, size_t ws_size,
                              hipStream_t stream) {
    const float* x   = (const float*)d_in[0];
    const int*   ei  = (const int*)d_in[1];
    const float* W0  = (const float*)d_in[2];
    const float* as0 = (const float*)d_in[3];
    const float* ad0 = (const float*)d_in[4];
    const float* b0  = (const float*)d_in[5];
    const float* g0  = (const float*)d_in[6];
    const float* bb0 = (const float*)d_in[7];
    const float* m0  = (const float*)d_in[8];
    const float* v0  = (const float*)d_in[9];
    const float* W1  = (const float*)d_in[10];
    const float* as1 = (const float*)d_in[11];
    const float* ad1 = (const float*)d_in[12];
    const float* b1  = (const float*)d_in[13];
    const float* g1  = (const float*)d_in[14];
    const float* bb1 = (const float*)d_in[15];
    const float* m1  = (const float*)d_in[16];
    const float* v1  = (const float*)d_in[17];
    const float* W2  = (const float*)d_in[18];
    const float* as2 = (const float*)d_in[19];
    const float* ad2 = (const float*)d_in[20];
    const float* b2  = (const float*)d_in[21];

    const int N  = in_sizes[0] / 128;
    const int E  = in_sizes[1] / 2;
    const int ET = E + N;
    const int NB = (N + 1023) / 1024;

    char* wsp = (char*)d_ws;
    int* row_ptr  = (int*)wsp;  wsp = align256(wsp + (size_t)(N + 1) * 4);
    int* cursor   = (int*)wsp;  wsp = align256(wsp + (size_t)N * 4);
    int* blocksum = (int*)wsp;  wsp = align256(wsp + (size_t)NB * 4);
    int* srcs     = (int*)wsp;  wsp = align256(wsp + (size_t)ET * 4);
    float* h      = (float*)wsp; wsp = align256(wsp + (size_t)N * 128 * 4);
    float* feat   = (float*)wsp; wsp = align256(wsp + (size_t)N * 128 * 4);
    float* asr    = (float*)wsp; wsp = align256(wsp + (size_t)N * 8 * 4);
    float* adt    = (float*)wsp; wsp = align256(wsp + (size_t)N * 8 * 4);
    float* emax   = (float*)wsp; wsp = align256(wsp + (size_t)N * 8 * 4);
    float* invd   = (float*)wsp; wsp = align256(wsp + (size_t)N * 8 * 4);

    // CSR build (once, reused by all 3 layers)
    hipMemsetAsync(cursor, 0, (size_t)N * 4, stream);
    count_kernel<<<(ET + 255) / 256, 256, 0, stream>>>(ei, cursor, E, N);
    block_sum_kernel<<<NB, 256, 0, stream>>>(cursor, blocksum, N);
    scan_sums_kernel<<<1, 256, 0, stream>>>(blocksum, row_ptr, NB, N);
    scan_write_kernel<<<NB, 256, 0, stream>>>(cursor, blocksum, row_ptr, N);
    hipMemsetAsync(cursor, 0, (size_t)N * 4, stream);
    scatter_kernel<<<(ET + 255) / 256, 256, 0, stream>>>(ei, row_ptr, cursor, srcs, E, N);

    const int gemm_grid = (N + 63) / 64;

    // layer 0: x -> feat
    gemm128_alpha_kernel<<<gemm_grid, 256, 0, stream>>>(x, W0, as0, ad0, h, asr, adt, N);
    maxsum_kernel<8><<<(N * 8 + 255) / 256, 256, 0, stream>>>(row_ptr, srcs, asr, adt, emax, invd, N);
    message128_kernel<<<(N + 7) / 8, 256, 0, stream>>>((const float4*)h, row_ptr, srcs, asr, adt,
                                                       emax, invd, b0, g0, bb0, m0, v0, feat, N);
    // layer 1: feat -> feat (reads h, safe in-place)
    gemm128_alpha_kernel<<<gemm_grid, 256, 0, stream>>>(feat, W1, as1, ad1, h, asr, adt, N);
    maxsum_kernel<8><<<(N * 8 + 255) / 256, 256, 0, stream>>>(row_ptr, srcs, asr, adt, emax, invd, N);
    message128_kernel<<<(N + 7) / 8, 256, 0, stream>>>((const float4*)h, row_ptr, srcs, asr, adt,
                                                       emax, invd, b1, g1, bb1, m1, v1, feat, N);
    // layer 2: feat -> d_out
    gemm40_alpha_kernel<<<gemm_grid, 256, 0, stream>>>(feat, W2, as2, ad2, h, asr, adt, N);
    maxsum_kernel<1><<<(N + 255) / 256, 256, 0, stream>>>(row_ptr, srcs, asr, adt, emax, invd, N);
    message40_kernel<<<(N + 15) / 16, 256, 0, stream>>>((const float4*)h, row_ptr, srcs, asr, adt,
                                                        emax, invd, b2, (float*)d_out, N);
}

// Round 5
// 338.973 us; speedup vs baseline: 3.2203x; 1.2910x over previous
//
#include <hip/hip_runtime.h>
#include <hip/hip_fp16.h>
#include <math.h>

constexpr float NEG_SLOPE = 0.2f;
constexpr float BN_EPS_C = 1e-5f;

// ---------------- CSR build ----------------

__global__ void count_kernel(const int* __restrict__ ei, int* __restrict__ counts,
                             int E, int N) {
    int i = blockIdx.x * blockDim.x + threadIdx.x;
    int ET = E + N;
    if (i >= ET) return;
    int d = (i < E) ? ei[E + i] : (i - E);
    atomicAdd(&counts[d], 1);
}

// Hierarchical scan: A) per-1024-chunk sums, B) scan chunk sums, C) local scan + write.

__global__ void block_sum_kernel(const int* __restrict__ counts, int* __restrict__ blocksums,
                                 int n) {
    __shared__ int sh[256];
    int b = blockIdx.x, t = threadIdx.x;
    int i0 = b * 1024 + t * 4;
    int s = 0;
#pragma unroll
    for (int q = 0; q < 4; ++q)
        if (i0 + q < n) s += counts[i0 + q];
    sh[t] = s;
    __syncthreads();
    for (int off = 128; off >= 1; off >>= 1) {
        if (t < off) sh[t] += sh[t + off];
        __syncthreads();
    }
    if (t == 0) blocksums[b] = sh[0];
}

__global__ void scan_sums_kernel(int* __restrict__ blocksums, int* __restrict__ row_ptr,
                                 int nb, int n) {
    __shared__ int sh[256];
    int t = threadIdx.x;
    int CH = (nb + 255) >> 8;
    int beg = t * CH, end = min(beg + CH, nb);
    int s = 0;
    for (int i = beg; i < end; ++i) s += blocksums[i];
    sh[t] = s;
    __syncthreads();
    for (int off = 1; off < 256; off <<= 1) {
        int v = (t >= off) ? sh[t - off] : 0;
        __syncthreads();
        sh[t] += v;
        __syncthreads();
    }
    int prefix = (t == 0) ? 0 : sh[t - 1];
    for (int i = beg; i < end; ++i) {
        int c = blocksums[i];
        blocksums[i] = prefix;   // becomes block prefix
        prefix += c;
    }
    if (t == 255) row_ptr[n] = sh[255];
}

__global__ void scan_write_kernel(const int* __restrict__ counts,
                                  const int* __restrict__ blockpref,
                                  int* __restrict__ row_ptr, int n) {
    __shared__ int sh[256];
    int b = blockIdx.x, t = threadIdx.x;
    int i0 = b * 1024 + t * 4;
    int c0 = (i0 + 0 < n) ? counts[i0 + 0] : 0;
    int c1 = (i0 + 1 < n) ? counts[i0 + 1] : 0;
    int c2 = (i0 + 2 < n) ? counts[i0 + 2] : 0;
    int c3 = (i0 + 3 < n) ? counts[i0 + 3] : 0;
    int ts = c0 + c1 + c2 + c3;
    sh[t] = ts;
    __syncthreads();
    for (int off = 1; off < 256; off <<= 1) {
        int v = (t >= off) ? sh[t - off] : 0;
        __syncthreads();
        sh[t] += v;
        __syncthreads();
    }
    int excl = ((t == 0) ? 0 : sh[t - 1]) + blockpref[b];
    if (i0 + 0 < n) row_ptr[i0 + 0] = excl;
    if (i0 + 1 < n) row_ptr[i0 + 1] = excl + c0;
    if (i0 + 2 < n) row_ptr[i0 + 2] = excl + c0 + c1;
    if (i0 + 3 < n) row_ptr[i0 + 3] = excl + c0 + c1 + c2;
}

__global__ void scatter_kernel(const int* __restrict__ ei, const int* __restrict__ row_ptr,
                               int* __restrict__ cursor, int* __restrict__ srcs, int E, int N) {
    int i = blockIdx.x * blockDim.x + threadIdx.x;
    int ET = E + N;
    if (i >= ET) return;
    int s, d;
    if (i < E) { s = ei[i]; d = ei[E + i]; }
    else       { s = i - E; d = s; }
    int pos = row_ptr[d] + atomicAdd(&cursor[d], 1);
    srcs[pos] = s;
}

// ---------------- GEMM 128: h = X @ W^T (+ per-head alphas), h stored fp16 ----------------
// 256 threads = 8 row-threads x 32 col-threads. Thread: 8 node-rows x 4 cols.

__global__ __launch_bounds__(256)
void gemm128_alpha_kernel(const float* __restrict__ X, const float* __restrict__ W,
                          const float* __restrict__ a_src, const float* __restrict__ a_dst,
                          uint2* __restrict__ hh, float* __restrict__ asrc,
                          float* __restrict__ adst, int N) {
    __shared__ float Xs[64][128];
    __shared__ float Wt[64][132];
    const int t = threadIdx.x;
    const int n0 = blockIdx.x * 64;
    const int tr = t >> 5;    // 0..7
    const int tc = t & 31;    // 0..31 ; cols 4*tc..4*tc+3

    // stage X tile (64x128), coalesced float4
#pragma unroll
    for (int i = 0; i < 8; ++i) {
        int lin = t + i * 256;
        int r = lin >> 5;
        int m = lin & 31;
        int gn = n0 + r;
        float4 v = make_float4(0.f, 0.f, 0.f, 0.f);
        if (gn < N) v = *reinterpret_cast<const float4*>(&X[(size_t)gn * 128 + 4 * m]);
        *reinterpret_cast<float4*>(&Xs[r][4 * m]) = v;
    }

    float4 acc[8];
#pragma unroll
    for (int i = 0; i < 8; ++i) acc[i] = make_float4(0.f, 0.f, 0.f, 0.f);

#pragma unroll 1
    for (int kh = 0; kh < 2; ++kh) {
        __syncthreads();   // Xs ready (kh=0) / previous Wt readers done (kh=1)
        // stage Wt[kl][j] = W[j][kh*64+kl]
#pragma unroll
        for (int i = 0; i < 8; ++i) {
            int lin = t + i * 256;
            int j = lin >> 4;
            int k4 = (lin & 15) << 2;
            float4 v = *reinterpret_cast<const float4*>(&W[(size_t)j * 128 + kh * 64 + k4]);
            Wt[k4 + 0][j] = v.x;
            Wt[k4 + 1][j] = v.y;
            Wt[k4 + 2][j] = v.z;
            Wt[k4 + 3][j] = v.w;
        }
        __syncthreads();

#pragma unroll 1
        for (int k0 = 0; k0 < 64; k0 += 4) {
            float4 wv0 = *reinterpret_cast<const float4*>(&Wt[k0 + 0][4 * tc]);
            float4 wv1 = *reinterpret_cast<const float4*>(&Wt[k0 + 1][4 * tc]);
            float4 wv2 = *reinterpret_cast<const float4*>(&Wt[k0 + 2][4 * tc]);
            float4 wv3 = *reinterpret_cast<const float4*>(&Wt[k0 + 3][4 * tc]);
#pragma unroll
            for (int i = 0; i < 8; ++i) {
                float4 xv = *reinterpret_cast<const float4*>(&Xs[tr + 8 * i][kh * 64 + k0]);
                acc[i].x += xv.x * wv0.x; acc[i].y += xv.x * wv0.y;
                acc[i].z += xv.x * wv0.z; acc[i].w += xv.x * wv0.w;
                acc[i].x += xv.y * wv1.x; acc[i].y += xv.y * wv1.y;
                acc[i].z += xv.y * wv1.z; acc[i].w += xv.y * wv1.w;
                acc[i].x += xv.z * wv2.x; acc[i].y += xv.z * wv2.y;
                acc[i].z += xv.z * wv2.z; acc[i].w += xv.z * wv2.w;
                acc[i].x += xv.w * wv3.x; acc[i].y += xv.w * wv3.y;
                acc[i].z += xv.w * wv3.z; acc[i].w += xv.w * wv3.w;
            }
        }
    }

    // epilogue: write h (fp16-packed) + per-head alpha partials (4 lanes per head quad)
    const int hd = tc >> 2;
    float4 av = *reinterpret_cast<const float4*>(&a_src[4 * tc]);
    float4 bv = *reinterpret_cast<const float4*>(&a_dst[4 * tc]);
#pragma unroll
    for (int i = 0; i < 8; ++i) {
        int gn = n0 + tr + 8 * i;
        bool ok = gn < N;
        if (ok) {
            __half2 pa = __floats2half2_rn(acc[i].x, acc[i].y);
            __half2 pb = __floats2half2_rn(acc[i].z, acc[i].w);
            uint2 u;
            u.x = *reinterpret_cast<unsigned*>(&pa);
            u.y = *reinterpret_cast<unsigned*>(&pb);
            hh[(size_t)gn * 32 + tc] = u;
        }
        float p = acc[i].x * av.x + acc[i].y * av.y + acc[i].z * av.z + acc[i].w * av.w;
        float q = acc[i].x * bv.x + acc[i].y * bv.y + acc[i].z * bv.z + acc[i].w * bv.w;
        p += __shfl_xor(p, 1, 4);
        p += __shfl_xor(p, 2, 4);
        q += __shfl_xor(q, 1, 4);
        q += __shfl_xor(q, 2, 4);
        if ((tc & 3) == 0 && ok) {
            asrc[(size_t)gn * 8 + hd] = p;
            adst[(size_t)gn * 8 + hd] = q;
        }
    }
}

// ---------------- GEMM 40: h2 = X @ W2^T (+ single-head alphas), fp32 out ----------------

__global__ __launch_bounds__(256)
void gemm40_alpha_kernel(const float* __restrict__ X, const float* __restrict__ W,
                         const float* __restrict__ a_src, const float* __restrict__ a_dst,
                         float* __restrict__ h, float* __restrict__ asrc,
                         float* __restrict__ adst, int N) {
    __shared__ float Xs[64][128];
    __shared__ float Wt[128][48];
    const int t = threadIdx.x;
    const int n0 = blockIdx.x * 64;
    const int tr = t >> 4;    // 0..15
    const int tc = t & 15;    // 0..15

#pragma unroll
    for (int i = 0; i < 8; ++i) {
        int lin = t + i * 256;
        int r = lin >> 5;
        int m = lin & 31;
        int gn = n0 + r;
        float4 v = make_float4(0.f, 0.f, 0.f, 0.f);
        if (gn < N) v = *reinterpret_cast<const float4*>(&X[(size_t)gn * 128 + 4 * m]);
        *reinterpret_cast<float4*>(&Xs[r][4 * m]) = v;
    }
    // stage Wt[k][j] = W[j][k]  (40 rows), j in 0..39
#pragma unroll
    for (int i = 0; i < 5; ++i) {
        int lin = t + i * 256;
        if (lin < 1280) {
            int j = lin >> 5;
            int k4 = (lin & 31) << 2;
            float4 v = *reinterpret_cast<const float4*>(&W[(size_t)j * 128 + k4]);
            Wt[k4 + 0][j] = v.x;
            Wt[k4 + 1][j] = v.y;
            Wt[k4 + 2][j] = v.z;
            Wt[k4 + 3][j] = v.w;
        }
    }
    // zero the pad cols 40..47
    for (int idx = t; idx < 128 * 8; idx += 256)
        Wt[idx >> 3][40 + (idx & 7)] = 0.f;
    __syncthreads();

    float acc[4][3];
#pragma unroll
    for (int i = 0; i < 4; ++i)
#pragma unroll
        for (int jj = 0; jj < 3; ++jj) acc[i][jj] = 0.f;

#pragma unroll 1
    for (int k0 = 0; k0 < 128; k0 += 4) {
        float4 xv[4];
#pragma unroll
        for (int i = 0; i < 4; ++i)
            xv[i] = *reinterpret_cast<const float4*>(&Xs[4 * tr + i][k0]);
#pragma unroll
        for (int q = 0; q < 4; ++q) {
            float w0 = Wt[k0 + q][tc];
            float w1 = Wt[k0 + q][tc + 16];
            float w2 = Wt[k0 + q][tc + 32];
#pragma unroll
            for (int i = 0; i < 4; ++i) {
                float xq = (q == 0) ? xv[i].x : (q == 1) ? xv[i].y : (q == 2) ? xv[i].z : xv[i].w;
                acc[i][0] += xq * w0;
                acc[i][1] += xq * w1;
                acc[i][2] += xq * w2;
            }
        }
    }

#pragma unroll
    for (int i = 0; i < 4; ++i) {
        int gn = n0 + 4 * tr + i;
        bool ok = gn < N;
        float ps = 0.f, pd = 0.f;
#pragma unroll
        for (int jj = 0; jj < 3; ++jj) {
            int j = tc + 16 * jj;
            bool jok = j < 40;
            float v = acc[i][jj];
            if (ok && jok) h[(size_t)gn * 40 + j] = v;
            ps += v * (jok ? a_src[j] : 0.f);
            pd += v * (jok ? a_dst[j] : 0.f);
        }
#pragma unroll
        for (int off = 1; off < 16; off <<= 1) {
            ps += __shfl_xor(ps, off, 16);
            pd += __shfl_xor(pd, off, 16);
        }
        if (tc == 0 && ok) { asrc[gn] = ps; adst[gn] = pd; }
    }
}

// ---------------- fused message + online softmax, F=128, H=8, fp16 gather ----------------
// 32 threads per node (4 channels each), 8 nodes per 256-thread block.

__global__ __launch_bounds__(256)
void message128_kernel(const uint2* __restrict__ hh, const int* __restrict__ row_ptr,
                       const int* __restrict__ srcs,
                       const float* __restrict__ asrc, const float* __restrict__ adst,
                       const float* __restrict__ bias,
                       const float* __restrict__ bn_g, const float* __restrict__ bn_b,
                       const float* __restrict__ bn_m, const float* __restrict__ bn_v,
                       float* __restrict__ out, int N) {
    int node = blockIdx.x * 8 + (threadIdx.x >> 5);
    if (node >= N) return;
    int tc = threadIdx.x & 31;
    int hd = tc >> 2;
    int beg = row_ptr[node], end = row_ptr[node + 1];
    float ad = adst[(size_t)node * 8 + hd];
    float m = -1e30f, ssum = 0.f;
    float4 acc = make_float4(0.f, 0.f, 0.f, 0.f);
    int j = beg;
    for (; j + 2 <= end; j += 2) {
        int s0 = srcs[j];
        int s1 = srcs[j + 1];
        uint2 u0 = hh[(size_t)s0 * 32 + tc];
        uint2 u1 = hh[(size_t)s1 * 32 + tc];
        float e0 = asrc[(size_t)s0 * 8 + hd] + ad;
        float e1 = asrc[(size_t)s1 * 8 + hd] + ad;
        e0 = (e0 > 0.f) ? e0 : NEG_SLOPE * e0;
        e1 = (e1 > 0.f) ? e1 : NEG_SLOPE * e1;
        float m2 = fmaxf(m, fmaxf(e0, e1));
        float sc = __expf(m - m2);
        float w0 = __expf(e0 - m2);
        float w1 = __expf(e1 - m2);
        m = m2;
        ssum = ssum * sc + w0 + w1;
        float2 f0a = __half22float2(*reinterpret_cast<const __half2*>(&u0.x));
        float2 f0b = __half22float2(*reinterpret_cast<const __half2*>(&u0.y));
        float2 f1a = __half22float2(*reinterpret_cast<const __half2*>(&u1.x));
        float2 f1b = __half22float2(*reinterpret_cast<const __half2*>(&u1.y));
        acc.x = acc.x * sc + w0 * f0a.x + w1 * f1a.x;
        acc.y = acc.y * sc + w0 * f0a.y + w1 * f1a.y;
        acc.z = acc.z * sc + w0 * f0b.x + w1 * f1b.x;
        acc.w = acc.w * sc + w0 * f0b.y + w1 * f1b.y;
    }
    if (j < end) {
        int s0 = srcs[j];
        uint2 u0 = hh[(size_t)s0 * 32 + tc];
        float e0 = asrc[(size_t)s0 * 8 + hd] + ad;
        e0 = (e0 > 0.f) ? e0 : NEG_SLOPE * e0;
        float m2 = fmaxf(m, e0);
        float sc = __expf(m - m2);
        float w0 = __expf(e0 - m2);
        m = m2;
        ssum = ssum * sc + w0;
        float2 f0a = __half22float2(*reinterpret_cast<const __half2*>(&u0.x));
        float2 f0b = __half22float2(*reinterpret_cast<const __half2*>(&u0.y));
        acc.x = acc.x * sc + w0 * f0a.x;
        acc.y = acc.y * sc + w0 * f0a.y;
        acc.z = acc.z * sc + w0 * f0b.x;
        acc.w = acc.w * sc + w0 * f0b.y;
    }
    float inv = 1.0f / (ssum + 1e-16f);
    acc.x *= inv; acc.y *= inv; acc.z *= inv; acc.w *= inv;

    int c = tc * 4;
    float4 bi = *reinterpret_cast<const float4*>(&bias[c]);
    float4 g  = *reinterpret_cast<const float4*>(&bn_g[c]);
    float4 bb = *reinterpret_cast<const float4*>(&bn_b[c]);
    float4 mm = *reinterpret_cast<const float4*>(&bn_m[c]);
    float4 vv = *reinterpret_cast<const float4*>(&bn_v[c]);
    float r[4];
    r[0] = (acc.x + bi.x - mm.x) * rsqrtf(vv.x + BN_EPS_C) * g.x + bb.x;
    r[1] = (acc.y + bi.y - mm.y) * rsqrtf(vv.y + BN_EPS_C) * g.y + bb.y;
    r[2] = (acc.z + bi.z - mm.z) * rsqrtf(vv.z + BN_EPS_C) * g.z + bb.z;
    r[3] = (acc.w + bi.w - mm.w) * rsqrtf(vv.w + BN_EPS_C) * g.w + bb.w;
#pragma unroll
    for (int q = 0; q < 4; ++q) r[q] = (r[q] > 0.f) ? r[q] : expm1f(r[q]);
    *reinterpret_cast<float4*>(&out[(size_t)node * 128 + c]) =
        make_float4(r[0], r[1], r[2], r[3]);
}

// ---------------- fused message + online softmax, F=40, H=1, fp32 gather ----------------
// 16 threads per node (lanes 0..9 active), 16 nodes per block.

__global__ __launch_bounds__(256)
void message40_kernel(const float4* __restrict__ h4, const int* __restrict__ row_ptr,
                      const int* __restrict__ srcs,
                      const float* __restrict__ asrc, const float* __restrict__ adst,
                      const float* __restrict__ b2, float* __restrict__ out, int N) {
    int node = blockIdx.x * 16 + (threadIdx.x >> 4);
    if (node >= N) return;
    int tc = threadIdx.x & 15;
    int beg = row_ptr[node], end = row_ptr[node + 1];
    float ad = adst[node];
    float m = -1e30f, ssum = 0.f;
    float4 acc = make_float4(0.f, 0.f, 0.f, 0.f);
    int j = beg;
    for (; j + 2 <= end; j += 2) {
        int s0 = srcs[j];
        int s1 = srcs[j + 1];
        float4 v0 = make_float4(0.f, 0.f, 0.f, 0.f);
        float4 v1 = make_float4(0.f, 0.f, 0.f, 0.f);
        if (tc < 10) {
            v0 = h4[(size_t)s0 * 10 + tc];
            v1 = h4[(size_t)s1 * 10 + tc];
        }
        float e0 = asrc[s0] + ad;
        float e1 = asrc[s1] + ad;
        e0 = (e0 > 0.f) ? e0 : NEG_SLOPE * e0;
        e1 = (e1 > 0.f) ? e1 : NEG_SLOPE * e1;
        float m2 = fmaxf(m, fmaxf(e0, e1));
        float sc = __expf(m - m2);
        float w0 = __expf(e0 - m2);
        float w1 = __expf(e1 - m2);
        m = m2;
        ssum = ssum * sc + w0 + w1;
        acc.x = acc.x * sc + w0 * v0.x + w1 * v1.x;
        acc.y = acc.y * sc + w0 * v0.y + w1 * v1.y;
        acc.z = acc.z * sc + w0 * v0.z + w1 * v1.z;
        acc.w = acc.w * sc + w0 * v0.w + w1 * v1.w;
    }
    if (j < end) {
        int s0 = srcs[j];
        float4 v0 = make_float4(0.f, 0.f, 0.f, 0.f);
        if (tc < 10) v0 = h4[(size_t)s0 * 10 + tc];
        float e0 = asrc[s0] + ad;
        e0 = (e0 > 0.f) ? e0 : NEG_SLOPE * e0;
        float m2 = fmaxf(m, e0);
        float sc = __expf(m - m2);
        float w0 = __expf(e0 - m2);
        m = m2;
        ssum = ssum * sc + w0;
        acc.x = acc.x * sc + w0 * v0.x;
        acc.y = acc.y * sc + w0 * v0.y;
        acc.z = acc.z * sc + w0 * v0.z;
        acc.w = acc.w * sc + w0 * v0.w;
    }
    if (tc < 10) {
        float inv = 1.0f / (ssum + 1e-16f);
        int c = tc * 4;
        float4 bi = *reinterpret_cast<const float4*>(&b2[c]);
        *reinterpret_cast<float4*>(&out[(size_t)node * 40 + c]) =
            make_float4(acc.x * inv + bi.x, acc.y * inv + bi.y,
                        acc.z * inv + bi.z, acc.w * inv + bi.w);
    }
}

// ---------------- launcher ----------------

static inline char* align256(char* p) {
    return (char*)(((uintptr_t)p + 255) & ~(uintptr_t)255);
}

extern "C" void kernel_launch(void* const* d_in, const int* in_sizes, int n_in,
                              void* d_out, int out_size, void* d_ws, size_t ws_size,
                              hipStream_t stream) {
    const float* x   = (const float*)d_in[0];
    const int*   ei  = (const int*)d_in[1];
    const float* W0  = (const float*)d_in[2];
    const float* as0 = (const float*)d_in[3];
    const float* ad0 = (const float*)d_in[4];
    const float* b0  = (const float*)d_in[5];
    const float* g0  = (const float*)d_in[6];
    const float* bb0 = (const float*)d_in[7];
    const float* m0  = (const float*)d_in[8];
    const float* v0  = (const float*)d_in[9];
    const float* W1  = (const float*)d_in[10];
    const float* as1 = (const float*)d_in[11];
    const float* ad1 = (const float*)d_in[12];
    const float* b1  = (const float*)d_in[13];
    const float* g1  = (const float*)d_in[14];
    const float* bb1 = (const float*)d_in[15];
    const float* m1  = (const float*)d_in[16];
    const float* v1  = (const float*)d_in[17];
    const float* W2  = (const float*)d_in[18];
    const float* as2 = (const float*)d_in[19];
    const float* ad2 = (const float*)d_in[20];
    const float* b2  = (const float*)d_in[21];

    const int N  = in_sizes[0] / 128;
    const int E  = in_sizes[1] / 2;
    const int ET = E + N;
    const int NB = (N + 1023) / 1024;

    char* wsp = (char*)d_ws;
    int* row_ptr  = (int*)wsp;   wsp = align256(wsp + (size_t)(N + 1) * 4);
    int* cursor   = (int*)wsp;   wsp = align256(wsp + (size_t)N * 4);
    int* blocksum = (int*)wsp;   wsp = align256(wsp + (size_t)NB * 4);
    int* srcs     = (int*)wsp;   wsp = align256(wsp + (size_t)ET * 4);
    uint2* hh     = (uint2*)wsp; wsp = align256(wsp + (size_t)N * 128 * 2);   // fp16 h
    float* h2     = (float*)wsp; wsp = align256(wsp + (size_t)N * 40 * 4);    // fp32 layer-2 h
    float* feat   = (float*)wsp; wsp = align256(wsp + (size_t)N * 128 * 4);
    float* asr    = (float*)wsp; wsp = align256(wsp + (size_t)N * 8 * 4);
    float* adt    = (float*)wsp; wsp = align256(wsp + (size_t)N * 8 * 4);

    // CSR build (once, reused by all 3 layers)
    hipMemsetAsync(cursor, 0, (size_t)N * 4, stream);
    count_kernel<<<(ET + 255) / 256, 256, 0, stream>>>(ei, cursor, E, N);
    block_sum_kernel<<<NB, 256, 0, stream>>>(cursor, blocksum, N);
    scan_sums_kernel<<<1, 256, 0, stream>>>(blocksum, row_ptr, NB, N);
    scan_write_kernel<<<NB, 256, 0, stream>>>(cursor, blocksum, row_ptr, N);
    hipMemsetAsync(cursor, 0, (size_t)N * 4, stream);
    scatter_kernel<<<(ET + 255) / 256, 256, 0, stream>>>(ei, row_ptr, cursor, srcs, E, N);

    const int gemm_grid = (N + 63) / 64;

    // layer 0: x -> feat
    gemm128_alpha_kernel<<<gemm_grid, 256, 0, stream>>>(x, W0, as0, ad0, hh, asr, adt, N);
    message128_kernel<<<(N + 7) / 8, 256, 0, stream>>>(hh, row_ptr, srcs, asr, adt,
                                                       b0, g0, bb0, m0, v0, feat, N);
    // layer 1: feat -> feat
    gemm128_alpha_kernel<<<gemm_grid, 256, 0, stream>>>(feat, W1, as1, ad1, hh, asr, adt, N);
    message128_kernel<<<(N + 7) / 8, 256, 0, stream>>>(hh, row_ptr, srcs, asr, adt,
                                                       b1, g1, bb1, m1, v1, feat, N);
    // layer 2: feat -> d_out
    gemm40_alpha_kernel<<<gemm_grid, 256, 0, stream>>>(feat, W2, as2, ad2, h2, asr, adt, N);
    message40_kernel<<<(N + 15) / 16, 256, 0, stream>>>((const float4*)h2, row_ptr, srcs,
                                                        asr, adt, b2, (float*)d_out, N);
}

// Round 6
// 306.144 us; speedup vs baseline: 3.5656x; 1.1072x over previous
//
#include <hip/hip_runtime.h>
#include <hip/hip_fp16.h>
#include <math.h>

constexpr float NEG_SLOPE = 0.2f;
constexpr float BN_EPS_C = 1e-5f;

using half8 = __attribute__((ext_vector_type(8))) _Float16;
using f32x4 = __attribute__((ext_vector_type(4))) float;

// ---------------- CSR build ----------------

__global__ void count_kernel(const int* __restrict__ ei, int* __restrict__ counts,
                             int E, int N) {
    int i = blockIdx.x * blockDim.x + threadIdx.x;
    int ET = E + N;
    if (i >= ET) return;
    int d = (i < E) ? ei[E + i] : (i - E);
    atomicAdd(&counts[d], 1);
}

__global__ void block_sum_kernel(const int* __restrict__ counts, int* __restrict__ blocksums,
                                 int n) {
    __shared__ int sh[256];
    int b = blockIdx.x, t = threadIdx.x;
    int i0 = b * 1024 + t * 4;
    int s = 0;
#pragma unroll
    for (int q = 0; q < 4; ++q)
        if (i0 + q < n) s += counts[i0 + q];
    sh[t] = s;
    __syncthreads();
    for (int off = 128; off >= 1; off >>= 1) {
        if (t < off) sh[t] += sh[t + off];
        __syncthreads();
    }
    if (t == 0) blocksums[b] = sh[0];
}

__global__ void scan_sums_kernel(int* __restrict__ blocksums, int* __restrict__ row_ptr,
                                 int nb, int n) {
    __shared__ int sh[256];
    int t = threadIdx.x;
    int CH = (nb + 255) >> 8;
    int beg = t * CH, end = min(beg + CH, nb);
    int s = 0;
    for (int i = beg; i < end; ++i) s += blocksums[i];
    sh[t] = s;
    __syncthreads();
    for (int off = 1; off < 256; off <<= 1) {
        int v = (t >= off) ? sh[t - off] : 0;
        __syncthreads();
        sh[t] += v;
        __syncthreads();
    }
    int prefix = (t == 0) ? 0 : sh[t - 1];
    for (int i = beg; i < end; ++i) {
        int c = blocksums[i];
        blocksums[i] = prefix;
        prefix += c;
    }
    if (t == 255) row_ptr[n] = sh[255];
}

__global__ void scan_write_kernel(const int* __restrict__ counts,
                                  const int* __restrict__ blockpref,
                                  int* __restrict__ row_ptr, int n) {
    __shared__ int sh[256];
    int b = blockIdx.x, t = threadIdx.x;
    int i0 = b * 1024 + t * 4;
    int c0 = (i0 + 0 < n) ? counts[i0 + 0] : 0;
    int c1 = (i0 + 1 < n) ? counts[i0 + 1] : 0;
    int c2 = (i0 + 2 < n) ? counts[i0 + 2] : 0;
    int c3 = (i0 + 3 < n) ? counts[i0 + 3] : 0;
    int ts = c0 + c1 + c2 + c3;
    sh[t] = ts;
    __syncthreads();
    for (int off = 1; off < 256; off <<= 1) {
        int v = (t >= off) ? sh[t - off] : 0;
        __syncthreads();
        sh[t] += v;
        __syncthreads();
    }
    int excl = ((t == 0) ? 0 : sh[t - 1]) + blockpref[b];
    if (i0 + 0 < n) row_ptr[i0 + 0] = excl;
    if (i0 + 1 < n) row_ptr[i0 + 1] = excl + c0;
    if (i0 + 2 < n) row_ptr[i0 + 2] = excl + c0 + c1;
    if (i0 + 3 < n) row_ptr[i0 + 3] = excl + c0 + c1 + c2;
}

__global__ void scatter_kernel(const int* __restrict__ ei, const int* __restrict__ row_ptr,
                               int* __restrict__ cursor, int* __restrict__ srcs, int E, int N) {
    int i = blockIdx.x * blockDim.x + threadIdx.x;
    int ET = E + N;
    if (i >= ET) return;
    int s, d;
    if (i < E) { s = ei[i]; d = ei[E + i]; }
    else       { s = i - E; d = s; }
    int pos = row_ptr[d] + atomicAdd(&cursor[d], 1);
    srcs[pos] = s;
}

// ---------------- MFMA GEMM 128: h(fp16) = X @ W^T (+ per-head alphas) ----------------
// Block = 64 rows x 128 cols, 4 waves (wave w: rows 16w..16w+15, all 128 cols).
// fp16 inputs (cast on staging), fp32 accumulate via mfma_f32_16x16x32_f16.
// A-frag: lane holds A[l&15][ (l>>4)*8 + j + 32ks ]; B-frag: B[k][col=l&15] from Bs[col][k].
// C/D: col=lane&15, row=(lane>>4)*4+reg.  LDS pad 136 halves (272B) -> 4-bank row rotation.

__global__ __launch_bounds__(256)
void gemm128_mfma_kernel(const float* __restrict__ X, const float* __restrict__ W,
                         const float* __restrict__ a_src, const float* __restrict__ a_dst,
                         __half* __restrict__ hp, float* __restrict__ asrc,
                         float* __restrict__ adst, int N) {
    __shared__ _Float16 Ah[64][136];
    __shared__ _Float16 Bs[128][136];
    const int t = threadIdx.x;
    const int n0 = blockIdx.x * 64;

    // stage A (X tile, 64x128 fp32 -> fp16)
#pragma unroll
    for (int i = 0; i < 8; ++i) {
        int lin = t + i * 256;
        int r = lin >> 5;
        int m = lin & 31;            // float4 index
        int gn = n0 + r;
        float4 v = make_float4(0.f, 0.f, 0.f, 0.f);
        if (gn < N) v = *reinterpret_cast<const float4*>(&X[(size_t)gn * 128 + 4 * m]);
        __half2 p0 = __floats2half2_rn(v.x, v.y);
        __half2 p1 = __floats2half2_rn(v.z, v.w);
        uint2 u;
        u.x = *reinterpret_cast<unsigned*>(&p0);
        u.y = *reinterpret_cast<unsigned*>(&p1);
        *reinterpret_cast<uint2*>(&Ah[r][4 * m]) = u;
    }
    // stage B (W, 128x128 fp32 -> fp16; Bs[n][k] = W[n][k])
#pragma unroll
    for (int i = 0; i < 16; ++i) {
        int lin = t + i * 256;
        int n = lin >> 5;
        int m = lin & 31;
        float4 v = *reinterpret_cast<const float4*>(&W[(size_t)n * 128 + 4 * m]);
        __half2 p0 = __floats2half2_rn(v.x, v.y);
        __half2 p1 = __floats2half2_rn(v.z, v.w);
        uint2 u;
        u.x = *reinterpret_cast<unsigned*>(&p0);
        u.y = *reinterpret_cast<unsigned*>(&p1);
        *reinterpret_cast<uint2*>(&Bs[n][4 * m]) = u;
    }
    __syncthreads();

    const int l  = t & 63;
    const int w  = t >> 6;
    const int lr = l & 15;
    const int lg = l >> 4;   // 0..3

    f32x4 acc[8];
#pragma unroll
    for (int tt = 0; tt < 8; ++tt) acc[tt] = (f32x4){0.f, 0.f, 0.f, 0.f};

#pragma unroll
    for (int ks = 0; ks < 4; ++ks) {
        half8 a = *reinterpret_cast<const half8*>(&Ah[16 * w + lr][8 * lg + 32 * ks]);
#pragma unroll
        for (int tt = 0; tt < 8; ++tt) {
            half8 b = *reinterpret_cast<const half8*>(&Bs[16 * tt + lr][8 * lg + 32 * ks]);
            acc[tt] = __builtin_amdgcn_mfma_f32_16x16x32_f16(a, b, acc[tt], 0, 0, 0);
        }
    }

    // epilogue: h (fp16) + per-head alphas (head hd == column tile tt)
    float av[8], bv[8];
#pragma unroll
    for (int tt = 0; tt < 8; ++tt) {
        av[tt] = a_src[16 * tt + lr];
        bv[tt] = a_dst[16 * tt + lr];
    }
#pragma unroll
    for (int reg = 0; reg < 4; ++reg) {
        int gr = n0 + 16 * w + 4 * lg + reg;
        bool ok = gr < N;
        if (ok) {
#pragma unroll
            for (int tt = 0; tt < 8; ++tt)
                hp[(size_t)gr * 128 + 16 * tt + lr] = __float2half(acc[tt][reg]);
        }
#pragma unroll
        for (int tt = 0; tt < 8; ++tt) {
            float p = acc[tt][reg] * av[tt];
            float q = acc[tt][reg] * bv[tt];
#pragma unroll
            for (int off = 1; off < 16; off <<= 1) {
                p += __shfl_xor(p, off, 16);
                q += __shfl_xor(q, off, 16);
            }
            if (ok && lr == tt) {
                asrc[(size_t)gr * 8 + tt] = p;
                adst[(size_t)gr * 8 + tt] = q;
            }
        }
    }
}

// ---------------- GEMM 40: h2 = X @ W2^T (+ single-head alphas), fp32 vector ----------------

__global__ __launch_bounds__(256)
void gemm40_alpha_kernel(const float* __restrict__ X, const float* __restrict__ W,
                         const float* __restrict__ a_src, const float* __restrict__ a_dst,
                         float* __restrict__ h, float* __restrict__ asrc,
                         float* __restrict__ adst, int N) {
    __shared__ float Xs[64][128];
    __shared__ float Wt[128][48];
    const int t = threadIdx.x;
    const int n0 = blockIdx.x * 64;
    const int tr = t >> 4;    // 0..15
    const int tc = t & 15;    // 0..15

#pragma unroll
    for (int i = 0; i < 8; ++i) {
        int lin = t + i * 256;
        int r = lin >> 5;
        int m = lin & 31;
        int gn = n0 + r;
        float4 v = make_float4(0.f, 0.f, 0.f, 0.f);
        if (gn < N) v = *reinterpret_cast<const float4*>(&X[(size_t)gn * 128 + 4 * m]);
        *reinterpret_cast<float4*>(&Xs[r][4 * m]) = v;
    }
#pragma unroll
    for (int i = 0; i < 5; ++i) {
        int lin = t + i * 256;
        if (lin < 1280) {
            int j = lin >> 5;
            int k4 = (lin & 31) << 2;
            float4 v = *reinterpret_cast<const float4*>(&W[(size_t)j * 128 + k4]);
            Wt[k4 + 0][j] = v.x;
            Wt[k4 + 1][j] = v.y;
            Wt[k4 + 2][j] = v.z;
            Wt[k4 + 3][j] = v.w;
        }
    }
    for (int idx = t; idx < 128 * 8; idx += 256)
        Wt[idx >> 3][40 + (idx & 7)] = 0.f;
    __syncthreads();

    float acc[4][3];
#pragma unroll
    for (int i = 0; i < 4; ++i)
#pragma unroll
        for (int jj = 0; jj < 3; ++jj) acc[i][jj] = 0.f;

#pragma unroll 1
    for (int k0 = 0; k0 < 128; k0 += 4) {
        float4 xv[4];
#pragma unroll
        for (int i = 0; i < 4; ++i)
            xv[i] = *reinterpret_cast<const float4*>(&Xs[4 * tr + i][k0]);
#pragma unroll
        for (int q = 0; q < 4; ++q) {
            float w0 = Wt[k0 + q][tc];
            float w1 = Wt[k0 + q][tc + 16];
            float w2 = Wt[k0 + q][tc + 32];
#pragma unroll
            for (int i = 0; i < 4; ++i) {
                float xq = (q == 0) ? xv[i].x : (q == 1) ? xv[i].y : (q == 2) ? xv[i].z : xv[i].w;
                acc[i][0] += xq * w0;
                acc[i][1] += xq * w1;
                acc[i][2] += xq * w2;
            }
        }
    }

#pragma unroll
    for (int i = 0; i < 4; ++i) {
        int gn = n0 + 4 * tr + i;
        bool ok = gn < N;
        float ps = 0.f, pd = 0.f;
#pragma unroll
        for (int jj = 0; jj < 3; ++jj) {
            int j = tc + 16 * jj;
            bool jok = j < 40;
            float v = acc[i][jj];
            if (ok && jok) h[(size_t)gn * 40 + j] = v;
            ps += v * (jok ? a_src[j] : 0.f);
            pd += v * (jok ? a_dst[j] : 0.f);
        }
#pragma unroll
        for (int off = 1; off < 16; off <<= 1) {
            ps += __shfl_xor(ps, off, 16);
            pd += __shfl_xor(pd, off, 16);
        }
        if (tc == 0 && ok) { asrc[gn] = ps; adst[gn] = pd; }
    }
}

// ---------------- fused message + softmax (direct exp), F=128, H=8, fp16 gather ----------------

__global__ __launch_bounds__(256)
void message128_kernel(const uint2* __restrict__ hh, const int* __restrict__ row_ptr,
                       const int* __restrict__ srcs,
                       const float* __restrict__ asrc, const float* __restrict__ adst,
                       const float* __restrict__ bias,
                       const float* __restrict__ bn_g, const float* __restrict__ bn_b,
                       const float* __restrict__ bn_m, const float* __restrict__ bn_v,
                       float* __restrict__ out, int N) {
    int node = blockIdx.x * 8 + (threadIdx.x >> 5);
    if (node >= N) return;
    int tc = threadIdx.x & 31;
    int hd = tc >> 2;
    int beg = row_ptr[node], end = row_ptr[node + 1];
    float ad = adst[(size_t)node * 8 + hd];
    float ssum = 0.f;
    float4 acc = make_float4(0.f, 0.f, 0.f, 0.f);
    int j = beg;
    for (; j + 2 <= end; j += 2) {
        int s0 = srcs[j];
        int s1 = srcs[j + 1];
        uint2 u0 = hh[(size_t)s0 * 32 + tc];
        uint2 u1 = hh[(size_t)s1 * 32 + tc];
        float e0 = asrc[(size_t)s0 * 8 + hd] + ad;
        float e1 = asrc[(size_t)s1 * 8 + hd] + ad;
        e0 = (e0 > 0.f) ? e0 : NEG_SLOPE * e0;
        e1 = (e1 > 0.f) ? e1 : NEG_SLOPE * e1;
        float w0 = __expf(e0);
        float w1 = __expf(e1);
        ssum += w0 + w1;
        float2 f0a = __half22float2(*reinterpret_cast<const __half2*>(&u0.x));
        float2 f0b = __half22float2(*reinterpret_cast<const __half2*>(&u0.y));
        float2 f1a = __half22float2(*reinterpret_cast<const __half2*>(&u1.x));
        float2 f1b = __half22float2(*reinterpret_cast<const __half2*>(&u1.y));
        acc.x += w0 * f0a.x + w1 * f1a.x;
        acc.y += w0 * f0a.y + w1 * f1a.y;
        acc.z += w0 * f0b.x + w1 * f1b.x;
        acc.w += w0 * f0b.y + w1 * f1b.y;
    }
    if (j < end) {
        int s0 = srcs[j];
        uint2 u0 = hh[(size_t)s0 * 32 + tc];
        float e0 = asrc[(size_t)s0 * 8 + hd] + ad;
        e0 = (e0 > 0.f) ? e0 : NEG_SLOPE * e0;
        float w0 = __expf(e0);
        ssum += w0;
        float2 f0a = __half22float2(*reinterpret_cast<const __half2*>(&u0.x));
        float2 f0b = __half22float2(*reinterpret_cast<const __half2*>(&u0.y));
        acc.x += w0 * f0a.x;
        acc.y += w0 * f0a.y;
        acc.z += w0 * f0b.x;
        acc.w += w0 * f0b.y;
    }
    float inv = 1.0f / (ssum + 1e-16f);
    acc.x *= inv; acc.y *= inv; acc.z *= inv; acc.w *= inv;

    int c = tc * 4;
    float4 bi = *reinterpret_cast<const float4*>(&bias[c]);
    float4 g  = *reinterpret_cast<const float4*>(&bn_g[c]);
    float4 bb = *reinterpret_cast<const float4*>(&bn_b[c]);
    float4 mm = *reinterpret_cast<const float4*>(&bn_m[c]);
    float4 vv = *reinterpret_cast<const float4*>(&bn_v[c]);
    float r[4];
    r[0] = (acc.x + bi.x - mm.x) * rsqrtf(vv.x + BN_EPS_C) * g.x + bb.x;
    r[1] = (acc.y + bi.y - mm.y) * rsqrtf(vv.y + BN_EPS_C) * g.y + bb.y;
    r[2] = (acc.z + bi.z - mm.z) * rsqrtf(vv.z + BN_EPS_C) * g.z + bb.z;
    r[3] = (acc.w + bi.w - mm.w) * rsqrtf(vv.w + BN_EPS_C) * g.w + bb.w;
#pragma unroll
    for (int q = 0; q < 4; ++q) r[q] = (r[q] > 0.f) ? r[q] : expm1f(r[q]);
    *reinterpret_cast<float4*>(&out[(size_t)node * 128 + c]) =
        make_float4(r[0], r[1], r[2], r[3]);
}

// ---------------- fused message + softmax (direct exp), F=40, H=1 ----------------

__global__ __launch_bounds__(256)
void message40_kernel(const float4* __restrict__ h4, const int* __restrict__ row_ptr,
                      const int* __restrict__ srcs,
                      const float* __restrict__ asrc, const float* __restrict__ adst,
                      const float* __restrict__ b2, float* __restrict__ out, int N) {
    int node = blockIdx.x * 16 + (threadIdx.x >> 4);
    if (node >= N) return;
    int tc = threadIdx.x & 15;
    int beg = row_ptr[node], end = row_ptr[node + 1];
    float ad = adst[node];
    float ssum = 0.f;
    float4 acc = make_float4(0.f, 0.f, 0.f, 0.f);
    int j = beg;
    for (; j + 2 <= end; j += 2) {
        int s0 = srcs[j];
        int s1 = srcs[j + 1];
        float4 v0 = make_float4(0.f, 0.f, 0.f, 0.f);
        float4 v1 = make_float4(0.f, 0.f, 0.f, 0.f);
        if (tc < 10) {
            v0 = h4[(size_t)s0 * 10 + tc];
            v1 = h4[(size_t)s1 * 10 + tc];
        }
        float e0 = asrc[s0] + ad;
        float e1 = asrc[s1] + ad;
        e0 = (e0 > 0.f) ? e0 : NEG_SLOPE * e0;
        e1 = (e1 > 0.f) ? e1 : NEG_SLOPE * e1;
        float w0 = __expf(e0);
        float w1 = __expf(e1);
        ssum += w0 + w1;
        acc.x += w0 * v0.x + w1 * v1.x;
        acc.y += w0 * v0.y + w1 * v1.y;
        acc.z += w0 * v0.z + w1 * v1.z;
        acc.w += w0 * v0.w + w1 * v1.w;
    }
    if (j < end) {
        int s0 = srcs[j];
        float4 v0 = make_float4(0.f, 0.f, 0.f, 0.f);
        if (tc < 10) v0 = h4[(size_t)s0 * 10 + tc];
        float e0 = asrc[s0] + ad;
        e0 = (e0 > 0.f) ? e0 : NEG_SLOPE * e0;
        float w0 = __expf(e0);
        ssum += w0;
        acc.x += w0 * v0.x;
        acc.y += w0 * v0.y;
        acc.z += w0 * v0.z;
        acc.w += w0 * v0.w;
    }
    if (tc < 10) {
        float inv = 1.0f / (ssum + 1e-16f);
        int c = tc * 4;
        float4 bi = *reinterpret_cast<const float4*>(&b2[c]);
        *reinterpret_cast<float4*>(&out[(size_t)node * 40 + c]) =
            make_float4(acc.x * inv + bi.x, acc.y * inv + bi.y,
                        acc.z * inv + bi.z, acc.w * inv + bi.w);
    }
}

// ---------------- launcher ----------------

static inline char* align256(char* p) {
    return (char*)(((uintptr_t)p + 255) & ~(uintptr_t)255);
}

extern "C" void kernel_launch(void* const* d_in, const int* in_sizes, int n_in,
                              void* d_out, int out_size, void* d_ws, size_t ws_size,
                              hipStream_t stream) {
    const float* x   = (const float*)d_in[0];
    const int*   ei  = (const int*)d_in[1];
    const float* W0  = (const float*)d_in[2];
    const float* as0 = (const float*)d_in[3];
    const float* ad0 = (const float*)d_in[4];
    const float* b0  = (const float*)d_in[5];
    const float* g0  = (const float*)d_in[6];
    const float* bb0 = (const float*)d_in[7];
    const float* m0  = (const float*)d_in[8];
    const float* v0  = (const float*)d_in[9];
    const float* W1  = (const float*)d_in[10];
    const float* as1 = (const float*)d_in[11];
    const float* ad1 = (const float*)d_in[12];
    const float* b1  = (const float*)d_in[13];
    const float* g1  = (const float*)d_in[14];
    const float* bb1 = (const float*)d_in[15];
    const float* m1  = (const float*)d_in[16];
    const float* v1  = (const float*)d_in[17];
    const float* W2  = (const float*)d_in[18];
    const float* as2 = (const float*)d_in[19];
    const float* ad2 = (const float*)d_in[20];
    const float* b2  = (const float*)d_in[21];

    const int N  = in_sizes[0] / 128;
    const int E  = in_sizes[1] / 2;
    const int ET = E + N;
    const int NB = (N + 1023) / 1024;

    char* wsp = (char*)d_ws;
    int* row_ptr  = (int*)wsp;   wsp = align256(wsp + (size_t)(N + 1) * 4);
    int* cursor   = (int*)wsp;   wsp = align256(wsp + (size_t)N * 4);
    int* blocksum = (int*)wsp;   wsp = align256(wsp + (size_t)NB * 4);
    int* srcs     = (int*)wsp;   wsp = align256(wsp + (size_t)ET * 4);
    uint2* hh     = (uint2*)wsp; wsp = align256(wsp + (size_t)N * 128 * 2);   // fp16 h
    float* h2     = (float*)wsp; wsp = align256(wsp + (size_t)N * 40 * 4);    // fp32 layer-2 h
    float* feat   = (float*)wsp; wsp = align256(wsp + (size_t)N * 128 * 4);
    float* asr    = (float*)wsp; wsp = align256(wsp + (size_t)N * 8 * 4);
    float* adt    = (float*)wsp; wsp = align256(wsp + (size_t)N * 8 * 4);

    // CSR build (once, reused by all 3 layers)
    hipMemsetAsync(cursor, 0, (size_t)N * 4, stream);
    count_kernel<<<(ET + 255) / 256, 256, 0, stream>>>(ei, cursor, E, N);
    block_sum_kernel<<<NB, 256, 0, stream>>>(cursor, blocksum, N);
    scan_sums_kernel<<<1, 256, 0, stream>>>(blocksum, row_ptr, NB, N);
    scan_write_kernel<<<NB, 256, 0, stream>>>(cursor, blocksum, row_ptr, N);
    hipMemsetAsync(cursor, 0, (size_t)N * 4, stream);
    scatter_kernel<<<(ET + 255) / 256, 256, 0, stream>>>(ei, row_ptr, cursor, srcs, E, N);

    const int gemm_grid = (N + 63) / 64;

    // layer 0: x -> feat
    gemm128_mfma_kernel<<<gemm_grid, 256, 0, stream>>>(x, W0, as0, ad0,
                                                       (__half*)hh, asr, adt, N);
    message128_kernel<<<(N + 7) / 8, 256, 0, stream>>>(hh, row_ptr, srcs, asr, adt,
                                                       b0, g0, bb0, m0, v0, feat, N);
    // layer 1: feat -> feat
    gemm128_mfma_kernel<<<gemm_grid, 256, 0, stream>>>(feat, W1, as1, ad1,
                                                       (__half*)hh, asr, adt, N);
    message128_kernel<<<(N + 7) / 8, 256, 0, stream>>>(hh, row_ptr, srcs, asr, adt,
                                                       b1, g1, bb1, m1, v1, feat, N);
    // layer 2: feat -> d_out
    gemm40_alpha_kernel<<<gemm_grid, 256, 0, stream>>>(feat, W2, as2, ad2, h2, asr, adt, N);
    message40_kernel<<<(N + 15) / 16, 256, 0, stream>>>((const float4*)h2, row_ptr, srcs,
                                                        asr, adt, b2, (float*)d_out, N);
}

// Round 7
// 279.378 us; speedup vs baseline: 3.9072x; 1.0958x over previous
//
#include <hip/hip_runtime.h>
#include <hip/hip_fp16.h>
#include <math.h>

constexpr float NEG_SLOPE = 0.2f;
constexpr float BN_EPS_C = 1e-5f;

using half8 = __attribute__((ext_vector_type(8))) _Float16;
using f32x4 = __attribute__((ext_vector_type(4))) float;

// ---------------- CSR build ----------------

__global__ void count_kernel(const int* __restrict__ ei, int* __restrict__ counts,
                             int E, int N) {
    int i = blockIdx.x * blockDim.x + threadIdx.x;
    int ET = E + N;
    if (i >= ET) return;
    int d = (i < E) ? ei[E + i] : (i - E);
    atomicAdd(&counts[d], 1);
}

__global__ void block_sum_kernel(const int* __restrict__ counts, int* __restrict__ blocksums,
                                 int n) {
    __shared__ int sh[256];
    int b = blockIdx.x, t = threadIdx.x;
    int i0 = b * 1024 + t * 4;
    int s = 0;
#pragma unroll
    for (int q = 0; q < 4; ++q)
        if (i0 + q < n) s += counts[i0 + q];
    sh[t] = s;
    __syncthreads();
    for (int off = 128; off >= 1; off >>= 1) {
        if (t < off) sh[t] += sh[t + off];
        __syncthreads();
    }
    if (t == 0) blocksums[b] = sh[0];
}

__global__ void scan_sums_kernel(int* __restrict__ blocksums, int* __restrict__ row_ptr,
                                 int nb, int n) {
    __shared__ int sh[256];
    int t = threadIdx.x;
    int CH = (nb + 255) >> 8;
    int beg = t * CH, end = min(beg + CH, nb);
    int s = 0;
    for (int i = beg; i < end; ++i) s += blocksums[i];
    sh[t] = s;
    __syncthreads();
    for (int off = 1; off < 256; off <<= 1) {
        int v = (t >= off) ? sh[t - off] : 0;
        __syncthreads();
        sh[t] += v;
        __syncthreads();
    }
    int prefix = (t == 0) ? 0 : sh[t - 1];
    for (int i = beg; i < end; ++i) {
        int c = blocksums[i];
        blocksums[i] = prefix;
        prefix += c;
    }
    if (t == 255) row_ptr[n] = sh[255];
}

__global__ void scan_write_kernel(const int* __restrict__ counts,
                                  const int* __restrict__ blockpref,
                                  int* __restrict__ row_ptr, int n) {
    __shared__ int sh[256];
    int b = blockIdx.x, t = threadIdx.x;
    int i0 = b * 1024 + t * 4;
    int c0 = (i0 + 0 < n) ? counts[i0 + 0] : 0;
    int c1 = (i0 + 1 < n) ? counts[i0 + 1] : 0;
    int c2 = (i0 + 2 < n) ? counts[i0 + 2] : 0;
    int c3 = (i0 + 3 < n) ? counts[i0 + 3] : 0;
    int ts = c0 + c1 + c2 + c3;
    sh[t] = ts;
    __syncthreads();
    for (int off = 1; off < 256; off <<= 1) {
        int v = (t >= off) ? sh[t - off] : 0;
        __syncthreads();
        sh[t] += v;
        __syncthreads();
    }
    int excl = ((t == 0) ? 0 : sh[t - 1]) + blockpref[b];
    if (i0 + 0 < n) row_ptr[i0 + 0] = excl;
    if (i0 + 1 < n) row_ptr[i0 + 1] = excl + c0;
    if (i0 + 2 < n) row_ptr[i0 + 2] = excl + c0 + c1;
    if (i0 + 3 < n) row_ptr[i0 + 3] = excl + c0 + c1 + c2;
}

__global__ void scatter_kernel(const int* __restrict__ ei, const int* __restrict__ row_ptr,
                               int* __restrict__ cursor, int* __restrict__ srcs, int E, int N) {
    int i = blockIdx.x * blockDim.x + threadIdx.x;
    int ET = E + N;
    if (i >= ET) return;
    int s, d;
    if (i < E) { s = ei[i]; d = ei[E + i]; }
    else       { s = i - E; d = s; }
    int pos = row_ptr[d] + atomicAdd(&cursor[d], 1);
    srcs[pos] = s;
}

// ---------------- MFMA GEMM 128: h(fp16) = X @ W^T (+ per-head alphas) ----------------
// Block = 128 rows x 128 cols, 512 threads (8 waves; wave w: rows 16w..16w+15).
// fp16 inputs (cast on staging), fp32 accumulate via mfma_f32_16x16x32_f16.
// C/D: col=lane&15, row=(lane>>4)*4+reg (verified passing in round 6).

__global__ __launch_bounds__(512)
void gemm128_mfma_kernel(const float* __restrict__ X, const float* __restrict__ W,
                         const float* __restrict__ a_src, const float* __restrict__ a_dst,
                         __half* __restrict__ hp, float* __restrict__ asrc,
                         float* __restrict__ adst, int N) {
    __shared__ _Float16 Ah[128][136];
    __shared__ _Float16 Bs[128][136];
    const int t = threadIdx.x;
    const int n0 = blockIdx.x * 128;

    // stage A (X tile, 128x128 fp32 -> fp16)
#pragma unroll
    for (int i = 0; i < 8; ++i) {
        int lin = t + i * 512;
        int r = lin >> 5;
        int m = lin & 31;
        int gn = n0 + r;
        float4 v = make_float4(0.f, 0.f, 0.f, 0.f);
        if (gn < N) v = *reinterpret_cast<const float4*>(&X[(size_t)gn * 128 + 4 * m]);
        __half2 p0 = __floats2half2_rn(v.x, v.y);
        __half2 p1 = __floats2half2_rn(v.z, v.w);
        uint2 u;
        u.x = *reinterpret_cast<unsigned*>(&p0);
        u.y = *reinterpret_cast<unsigned*>(&p1);
        *reinterpret_cast<uint2*>(&Ah[r][4 * m]) = u;
    }
    // stage B (W, 128x128 fp32 -> fp16)
#pragma unroll
    for (int i = 0; i < 8; ++i) {
        int lin = t + i * 512;
        int n = lin >> 5;
        int m = lin & 31;
        float4 v = *reinterpret_cast<const float4*>(&W[(size_t)n * 128 + 4 * m]);
        __half2 p0 = __floats2half2_rn(v.x, v.y);
        __half2 p1 = __floats2half2_rn(v.z, v.w);
        uint2 u;
        u.x = *reinterpret_cast<unsigned*>(&p0);
        u.y = *reinterpret_cast<unsigned*>(&p1);
        *reinterpret_cast<uint2*>(&Bs[n][4 * m]) = u;
    }
    __syncthreads();

    const int l  = t & 63;
    const int w  = t >> 6;   // 0..7
    const int lr = l & 15;
    const int lg = l >> 4;   // 0..3

    f32x4 acc[8];
#pragma unroll
    for (int tt = 0; tt < 8; ++tt) acc[tt] = (f32x4){0.f, 0.f, 0.f, 0.f};

#pragma unroll
    for (int ks = 0; ks < 4; ++ks) {
        half8 a = *reinterpret_cast<const half8*>(&Ah[16 * w + lr][8 * lg + 32 * ks]);
#pragma unroll
        for (int tt = 0; tt < 8; ++tt) {
            half8 b = *reinterpret_cast<const half8*>(&Bs[16 * tt + lr][8 * lg + 32 * ks]);
            acc[tt] = __builtin_amdgcn_mfma_f32_16x16x32_f16(a, b, acc[tt], 0, 0, 0);
        }
    }

    // epilogue: h (fp16) + per-head alphas (head == column tile tt)
    float av[8], bv[8];
#pragma unroll
    for (int tt = 0; tt < 8; ++tt) {
        av[tt] = a_src[16 * tt + lr];
        bv[tt] = a_dst[16 * tt + lr];
    }
#pragma unroll
    for (int reg = 0; reg < 4; ++reg) {
        int gr = n0 + 16 * w + 4 * lg + reg;
        bool ok = gr < N;
        if (ok) {
#pragma unroll
            for (int tt = 0; tt < 8; ++tt)
                hp[(size_t)gr * 128 + 16 * tt + lr] = __float2half(acc[tt][reg]);
        }
#pragma unroll
        for (int tt = 0; tt < 8; ++tt) {
            float p = acc[tt][reg] * av[tt];
            float q = acc[tt][reg] * bv[tt];
#pragma unroll
            for (int off = 1; off < 16; off <<= 1) {
                p += __shfl_xor(p, off, 16);
                q += __shfl_xor(q, off, 16);
            }
            if (ok && lr == tt) {
                asrc[(size_t)gr * 8 + tt] = p;
                adst[(size_t)gr * 8 + tt] = q;
            }
        }
    }
}

// ---------------- MFMA GEMM 40: h2(fp16) = X @ W2^T (+ single-head alphas) ----------------
// Block = 64 rows, 256 threads (4 waves; wave w: rows 16w..16w+15), col tiles tt=0..2 (48 cols,
// rows 40..47 of Bs zeroed).

__global__ __launch_bounds__(256)
void gemm40_mfma_kernel(const float* __restrict__ X, const float* __restrict__ W,
                        const float* __restrict__ a_src, const float* __restrict__ a_dst,
                        __half* __restrict__ hp, float* __restrict__ asrc,
                        float* __restrict__ adst, int N) {
    __shared__ _Float16 Ah[64][136];
    __shared__ _Float16 Bs[48][136];
    const int t = threadIdx.x;
    const int n0 = blockIdx.x * 64;

    // stage A (64x128)
#pragma unroll
    for (int i = 0; i < 8; ++i) {
        int lin = t + i * 256;
        int r = lin >> 5;
        int m = lin & 31;
        int gn = n0 + r;
        float4 v = make_float4(0.f, 0.f, 0.f, 0.f);
        if (gn < N) v = *reinterpret_cast<const float4*>(&X[(size_t)gn * 128 + 4 * m]);
        __half2 p0 = __floats2half2_rn(v.x, v.y);
        __half2 p1 = __floats2half2_rn(v.z, v.w);
        uint2 u;
        u.x = *reinterpret_cast<unsigned*>(&p0);
        u.y = *reinterpret_cast<unsigned*>(&p1);
        *reinterpret_cast<uint2*>(&Ah[r][4 * m]) = u;
    }
    // stage B (48x128; rows >= 40 zero)
#pragma unroll
    for (int i = 0; i < 6; ++i) {
        int lin = t + i * 256;
        if (lin < 1536) {
            int n = lin >> 5;
            int m = lin & 31;
            float4 v = make_float4(0.f, 0.f, 0.f, 0.f);
            if (n < 40) v = *reinterpret_cast<const float4*>(&W[(size_t)n * 128 + 4 * m]);
            __half2 p0 = __floats2half2_rn(v.x, v.y);
            __half2 p1 = __floats2half2_rn(v.z, v.w);
            uint2 u;
            u.x = *reinterpret_cast<unsigned*>(&p0);
            u.y = *reinterpret_cast<unsigned*>(&p1);
            *reinterpret_cast<uint2*>(&Bs[n][4 * m]) = u;
        }
    }
    __syncthreads();

    const int l  = t & 63;
    const int w  = t >> 6;
    const int lr = l & 15;
    const int lg = l >> 4;

    f32x4 acc[3];
#pragma unroll
    for (int tt = 0; tt < 3; ++tt) acc[tt] = (f32x4){0.f, 0.f, 0.f, 0.f};

#pragma unroll
    for (int ks = 0; ks < 4; ++ks) {
        half8 a = *reinterpret_cast<const half8*>(&Ah[16 * w + lr][8 * lg + 32 * ks]);
#pragma unroll
        for (int tt = 0; tt < 3; ++tt) {
            half8 b = *reinterpret_cast<const half8*>(&Bs[16 * tt + lr][8 * lg + 32 * ks]);
            acc[tt] = __builtin_amdgcn_mfma_f32_16x16x32_f16(a, b, acc[tt], 0, 0, 0);
        }
    }

    float av[3], bv[3];
#pragma unroll
    for (int tt = 0; tt < 3; ++tt) {
        int j = 16 * tt + lr;
        av[tt] = (j < 40) ? a_src[j] : 0.f;
        bv[tt] = (j < 40) ? a_dst[j] : 0.f;
    }
#pragma unroll
    for (int reg = 0; reg < 4; ++reg) {
        int gr = n0 + 16 * w + 4 * lg + reg;
        bool ok = gr < N;
        float p = 0.f, q = 0.f;
#pragma unroll
        for (int tt = 0; tt < 3; ++tt) {
            int j = 16 * tt + lr;
            if (ok && j < 40) hp[(size_t)gr * 40 + j] = __float2half(acc[tt][reg]);
            p += acc[tt][reg] * av[tt];
            q += acc[tt][reg] * bv[tt];
        }
#pragma unroll
        for (int off = 1; off < 16; off <<= 1) {
            p += __shfl_xor(p, off, 16);
            q += __shfl_xor(q, off, 16);
        }
        if (ok && lr == 0) {
            asrc[gr] = p;
            adst[gr] = q;
        }
    }
}

// ---------------- fused message + softmax, F=128, H=8 ----------------
// 32 lanes per node; two edges in flight (lane bit4 selects edge), 16 lanes/edge,
// uint4 (8 fp16 channels) per lane.  Combine halves with one shfl_xor(16).

__global__ __launch_bounds__(256)
void message128_kernel(const uint4* __restrict__ hh4, const int* __restrict__ row_ptr,
                       const int* __restrict__ srcs,
                       const float* __restrict__ asrc, const float* __restrict__ adst,
                       const float* __restrict__ bias,
                       const float* __restrict__ bn_g, const float* __restrict__ bn_b,
                       const float* __restrict__ bn_m, const float* __restrict__ bn_v,
                       float* __restrict__ out, int N) {
    int node = blockIdx.x * 8 + (threadIdx.x >> 5);
    if (node >= N) return;
    int tc = threadIdx.x & 31;
    int half_id = tc >> 4;   // which edge of the pair
    int cl = tc & 15;        // channel slot: ch 8*cl .. 8*cl+7
    int hd = cl >> 1;        // head
    int beg = row_ptr[node], end = row_ptr[node + 1];
    float ad = adst[(size_t)node * 8 + hd];
    float ssum = 0.f;
    float acc[8];
#pragma unroll
    for (int q = 0; q < 8; ++q) acc[q] = 0.f;

    int j = beg;
    for (; j + 2 <= end; j += 2) {
        int s = srcs[j + half_id];
        uint4 u = hh4[(size_t)s * 16 + cl];
        float e = asrc[(size_t)s * 8 + hd] + ad;
        e = (e > 0.f) ? e : NEG_SLOPE * e;
        float wgt = __expf(e);
        ssum += wgt;
        float2 f0 = __half22float2(*reinterpret_cast<const __half2*>(&u.x));
        float2 f1 = __half22float2(*reinterpret_cast<const __half2*>(&u.y));
        float2 f2 = __half22float2(*reinterpret_cast<const __half2*>(&u.z));
        float2 f3 = __half22float2(*reinterpret_cast<const __half2*>(&u.w));
        acc[0] += wgt * f0.x; acc[1] += wgt * f0.y;
        acc[2] += wgt * f1.x; acc[3] += wgt * f1.y;
        acc[4] += wgt * f2.x; acc[5] += wgt * f2.y;
        acc[6] += wgt * f3.x; acc[7] += wgt * f3.y;
    }
    if (j < end && half_id == 0) {
        int s = srcs[j];
        uint4 u = hh4[(size_t)s * 16 + cl];
        float e = asrc[(size_t)s * 8 + hd] + ad;
        e = (e > 0.f) ? e : NEG_SLOPE * e;
        float wgt = __expf(e);
        ssum += wgt;
        float2 f0 = __half22float2(*reinterpret_cast<const __half2*>(&u.x));
        float2 f1 = __half22float2(*reinterpret_cast<const __half2*>(&u.y));
        float2 f2 = __half22float2(*reinterpret_cast<const __half2*>(&u.z));
        float2 f3 = __half22float2(*reinterpret_cast<const __half2*>(&u.w));
        acc[0] += wgt * f0.x; acc[1] += wgt * f0.y;
        acc[2] += wgt * f1.x; acc[3] += wgt * f1.y;
        acc[4] += wgt * f2.x; acc[5] += wgt * f2.y;
        acc[6] += wgt * f3.x; acc[7] += wgt * f3.y;
    }
    // combine the two edge-halves (lane ^ 16 is the same node, same channels)
    ssum += __shfl_xor(ssum, 16);
#pragma unroll
    for (int q = 0; q < 8; ++q) acc[q] += __shfl_xor(acc[q], 16);

    if (half_id == 0) {
        float inv = 1.0f / (ssum + 1e-16f);
        int c = cl * 8;
        float r[8];
#pragma unroll
        for (int pp = 0; pp < 2; ++pp) {
            int cc = c + 4 * pp;
            float4 bi = *reinterpret_cast<const float4*>(&bias[cc]);
            float4 g  = *reinterpret_cast<const float4*>(&bn_g[cc]);
            float4 bb = *reinterpret_cast<const float4*>(&bn_b[cc]);
            float4 mm = *reinterpret_cast<const float4*>(&bn_m[cc]);
            float4 vv = *reinterpret_cast<const float4*>(&bn_v[cc]);
            r[4 * pp + 0] = (acc[4 * pp + 0] * inv + bi.x - mm.x) * rsqrtf(vv.x + BN_EPS_C) * g.x + bb.x;
            r[4 * pp + 1] = (acc[4 * pp + 1] * inv + bi.y - mm.y) * rsqrtf(vv.y + BN_EPS_C) * g.y + bb.y;
            r[4 * pp + 2] = (acc[4 * pp + 2] * inv + bi.z - mm.z) * rsqrtf(vv.z + BN_EPS_C) * g.z + bb.z;
            r[4 * pp + 3] = (acc[4 * pp + 3] * inv + bi.w - mm.w) * rsqrtf(vv.w + BN_EPS_C) * g.w + bb.w;
        }
#pragma unroll
        for (int q = 0; q < 8; ++q) r[q] = (r[q] > 0.f) ? r[q] : expm1f(r[q]);
        *reinterpret_cast<float4*>(&out[(size_t)node * 128 + c]) =
            make_float4(r[0], r[1], r[2], r[3]);
        *reinterpret_cast<float4*>(&out[(size_t)node * 128 + c + 4]) =
            make_float4(r[4], r[5], r[6], r[7]);
    }
}

// ---------------- fused message + softmax, F=40, H=1, fp16 gather ----------------

__global__ __launch_bounds__(256)
void message40_kernel(const uint2* __restrict__ hh2, const int* __restrict__ row_ptr,
                      const int* __restrict__ srcs,
                      const float* __restrict__ asrc, const float* __restrict__ adst,
                      const float* __restrict__ b2, float* __restrict__ out, int N) {
    int node = blockIdx.x * 16 + (threadIdx.x >> 4);
    if (node >= N) return;
    int tc = threadIdx.x & 15;
    int beg = row_ptr[node], end = row_ptr[node + 1];
    float ad = adst[node];
    float ssum = 0.f;
    float4 acc = make_float4(0.f, 0.f, 0.f, 0.f);
    int j = beg;
    for (; j + 2 <= end; j += 2) {
        int s0 = srcs[j];
        int s1 = srcs[j + 1];
        uint2 u0 = make_uint2(0u, 0u), u1 = make_uint2(0u, 0u);
        if (tc < 10) {
            u0 = hh2[(size_t)s0 * 10 + tc];
            u1 = hh2[(size_t)s1 * 10 + tc];
        }
        float e0 = asrc[s0] + ad;
        float e1 = asrc[s1] + ad;
        e0 = (e0 > 0.f) ? e0 : NEG_SLOPE * e0;
        e1 = (e1 > 0.f) ? e1 : NEG_SLOPE * e1;
        float w0 = __expf(e0);
        float w1 = __expf(e1);
        ssum += w0 + w1;
        float2 a0 = __half22float2(*reinterpret_cast<const __half2*>(&u0.x));
        float2 b0 = __half22float2(*reinterpret_cast<const __half2*>(&u0.y));
        float2 a1 = __half22float2(*reinterpret_cast<const __half2*>(&u1.x));
        float2 b1 = __half22float2(*reinterpret_cast<const __half2*>(&u1.y));
        acc.x += w0 * a0.x + w1 * a1.x;
        acc.y += w0 * a0.y + w1 * a1.y;
        acc.z += w0 * b0.x + w1 * b1.x;
        acc.w += w0 * b0.y + w1 * b1.y;
    }
    if (j < end) {
        int s0 = srcs[j];
        uint2 u0 = make_uint2(0u, 0u);
        if (tc < 10) u0 = hh2[(size_t)s0 * 10 + tc];
        float e0 = asrc[s0] + ad;
        e0 = (e0 > 0.f) ? e0 : NEG_SLOPE * e0;
        float w0 = __expf(e0);
        ssum += w0;
        float2 a0 = __half22float2(*reinterpret_cast<const __half2*>(&u0.x));
        float2 b0 = __half22float2(*reinterpret_cast<const __half2*>(&u0.y));
        acc.x += w0 * a0.x;
        acc.y += w0 * a0.y;
        acc.z += w0 * b0.x;
        acc.w += w0 * b0.y;
    }
    if (tc < 10) {
        float inv = 1.0f / (ssum + 1e-16f);
        int c = tc * 4;
        float4 bi = *reinterpret_cast<const float4*>(&b2[c]);
        *reinterpret_cast<float4*>(&out[(size_t)node * 40 + c]) =
            make_float4(acc.x * inv + bi.x, acc.y * inv + bi.y,
                        acc.z * inv + bi.z, acc.w * inv + bi.w);
    }
}

// ---------------- launcher ----------------

static inline char* align256(char* p) {
    return (char*)(((uintptr_t)p + 255) & ~(uintptr_t)255);
}

extern "C" void kernel_launch(void* const* d_in, const int* in_sizes, int n_in,
                              void* d_out, int out_size, void* d_ws, size_t ws_size,
                              hipStream_t stream) {
    const float* x   = (const float*)d_in[0];
    const int*   ei  = (const int*)d_in[1];
    const float* W0  = (const float*)d_in[2];
    const float* as0 = (const float*)d_in[3];
    const float* ad0 = (const float*)d_in[4];
    const float* b0  = (const float*)d_in[5];
    const float* g0  = (const float*)d_in[6];
    const float* bb0 = (const float*)d_in[7];
    const float* m0  = (const float*)d_in[8];
    const float* v0  = (const float*)d_in[9];
    const float* W1  = (const float*)d_in[10];
    const float* as1 = (const float*)d_in[11];
    const float* ad1 = (const float*)d_in[12];
    const float* b1  = (const float*)d_in[13];
    const float* g1  = (const float*)d_in[14];
    const float* bb1 = (const float*)d_in[15];
    const float* m1  = (const float*)d_in[16];
    const float* v1  = (const float*)d_in[17];
    const float* W2  = (const float*)d_in[18];
    const float* as2 = (const float*)d_in[19];
    const float* ad2 = (const float*)d_in[20];
    const float* b2  = (const float*)d_in[21];

    const int N  = in_sizes[0] / 128;
    const int E  = in_sizes[1] / 2;
    const int ET = E + N;
    const int NB = (N + 1023) / 1024;

    char* wsp = (char*)d_ws;
    int* row_ptr  = (int*)wsp;   wsp = align256(wsp + (size_t)(N + 1) * 4);
    int* cursor   = (int*)wsp;   wsp = align256(wsp + (size_t)N * 4);
    int* blocksum = (int*)wsp;   wsp = align256(wsp + (size_t)NB * 4);
    int* srcs     = (int*)wsp;   wsp = align256(wsp + (size_t)ET * 4);
    __half* hh    = (__half*)wsp; wsp = align256(wsp + (size_t)N * 128 * 2);  // fp16 h (layers 0/1)
    __half* h2    = (__half*)wsp; wsp = align256(wsp + (size_t)N * 40 * 2);   // fp16 layer-2 h
    float* feat   = (float*)wsp;  wsp = align256(wsp + (size_t)N * 128 * 4);
    float* asr    = (float*)wsp;  wsp = align256(wsp + (size_t)N * 8 * 4);
    float* adt    = (float*)wsp;  wsp = align256(wsp + (size_t)N * 8 * 4);

    // CSR build (once, reused by all 3 layers)
    hipMemsetAsync(cursor, 0, (size_t)N * 4, stream);
    count_kernel<<<(ET + 255) / 256, 256, 0, stream>>>(ei, cursor, E, N);
    block_sum_kernel<<<NB, 256, 0, stream>>>(cursor, blocksum, N);
    scan_sums_kernel<<<1, 256, 0, stream>>>(blocksum, row_ptr, NB, N);
    scan_write_kernel<<<NB, 256, 0, stream>>>(cursor, blocksum, row_ptr, N);
    hipMemsetAsync(cursor, 0, (size_t)N * 4, stream);
    scatter_kernel<<<(ET + 255) / 256, 256, 0, stream>>>(ei, row_ptr, cursor, srcs, E, N);

    const int g128 = (N + 127) / 128;
    const int g40  = (N + 63) / 64;

    // layer 0: x -> feat
    gemm128_mfma_kernel<<<g128, 512, 0, stream>>>(x, W0, as0, ad0, hh, asr, adt, N);
    message128_kernel<<<(N + 7) / 8, 256, 0, stream>>>((const uint4*)hh, row_ptr, srcs, asr, adt,
                                                       b0, g0, bb0, m0, v0, feat, N);
    // layer 1: feat -> feat
    gemm128_mfma_kernel<<<g128, 512, 0, stream>>>(feat, W1, as1, ad1, hh, asr, adt, N);
    message128_kernel<<<(N + 7) / 8, 256, 0, stream>>>((const uint4*)hh, row_ptr, srcs, asr, adt,
                                                       b1, g1, bb1, m1, v1, feat, N);
    // layer 2: feat -> d_out
    gemm40_mfma_kernel<<<g40, 256, 0, stream>>>(feat, W2, as2, ad2, h2, asr, adt, N);
    message40_kernel<<<(N + 15) / 16, 256, 0, stream>>>((const uint2*)h2, row_ptr, srcs,
                                                        asr, adt, b2, (float*)d_out, N);
}

// Round 8
// 225.082 us; speedup vs baseline: 4.8497x; 1.2412x over previous
//
#include <hip/hip_runtime.h>
#include <hip/hip_fp16.h>
#include <math.h>

constexpr float NEG_SLOPE = 0.2f;
constexpr float BN_EPS_C = 1e-5f;

using half8 = __attribute__((ext_vector_type(8))) _Float16;
using f32x4 = __attribute__((ext_vector_type(4))) float;

// ================= CSR build: LDS-binned two-level counting sort =================
// bucket = dst >> 8  (256 nodes per bucket; N=50k -> 196 buckets)

__global__ __launch_bounds__(256)
void bucket_hist_kernel(const int* __restrict__ ei, int* __restrict__ bucket_count,
                        int E, int N) {
    __shared__ int h[256];
    int t = threadIdx.x;
    h[t] = 0;
    __syncthreads();
    int base = blockIdx.x * 4096;
    int ET = E + N;
#pragma unroll
    for (int q = 0; q < 16; ++q) {
        int i = base + q * 256 + t;
        if (i < ET) {
            int d = (i < E) ? ei[E + i] : (i - E);
            atomicAdd(&h[d >> 8], 1);
        }
    }
    __syncthreads();
    if (h[t] > 0) atomicAdd(&bucket_count[t], h[t]);
}

__global__ __launch_bounds__(256)
void bucket_scan_kernel(const int* __restrict__ bucket_count, int* __restrict__ bucket_ptr,
                        int* __restrict__ gcursor, int* __restrict__ row_ptr,
                        int N, int ET) {
    __shared__ int s[256];
    int t = threadIdx.x;
    int c = bucket_count[t];
    s[t] = c;
    __syncthreads();
    for (int off = 1; off < 256; off <<= 1) {
        int v = (t >= off) ? s[t - off] : 0;
        __syncthreads();
        s[t] += v;
        __syncthreads();
    }
    int excl = s[t] - c;
    bucket_ptr[t] = excl;
    gcursor[t] = excl;
    if (t == 255) {
        bucket_ptr[256] = s[255];
        row_ptr[N] = ET;
    }
}

__global__ __launch_bounds__(256)
void bucket_bin_kernel(const int* __restrict__ ei, int* __restrict__ gcursor,
                       int2* __restrict__ tmp, int E, int N) {
    __shared__ int2 bins[4096];          // 32 KB
    __shared__ int lcount[256];
    __shared__ int lofs[256];
    __shared__ int lbase[256];
    __shared__ int lcur[256];
    int t = threadIdx.x;
    lcount[t] = 0;
    __syncthreads();
    int base = blockIdx.x * 4096;
    int ET = E + N;
    int2 pr[16];
#pragma unroll
    for (int q = 0; q < 16; ++q) {
        int i = base + q * 256 + t;
        pr[q] = make_int2(-1, -1);
        if (i < ET) {
            int s, d;
            if (i < E) { s = ei[i]; d = ei[E + i]; }
            else       { s = i - E; d = s; }
            pr[q] = make_int2(d, s);
            atomicAdd(&lcount[d >> 8], 1);
        }
    }
    __syncthreads();
    // exclusive scan of lcount -> lofs; reserve global space per bucket
    {
        int c = lcount[t];
        lofs[t] = c;
        __syncthreads();
        for (int off = 1; off < 256; off <<= 1) {
            int v = (t >= off) ? lofs[t - off] : 0;
            __syncthreads();
            lofs[t] += v;
            __syncthreads();
        }
        int excl = lofs[t] - c;
        __syncthreads();
        lofs[t] = excl;
        lcur[t] = excl;
        if (c > 0) lbase[t] = atomicAdd(&gcursor[t], c);
    }
    __syncthreads();
    // place pairs into LDS bins grouped by bucket
#pragma unroll
    for (int q = 0; q < 16; ++q) {
        if (pr[q].x >= 0) {
            int b = pr[q].x >> 8;
            int p = atomicAdd(&lcur[b], 1);
            bins[p] = pr[q];
        }
    }
    __syncthreads();
    // flush: consecutive p -> mostly same bucket -> coalesced bursts
    int total = min(4096, ET - base);
    for (int p = t; p < total; p += 256) {
        int2 e = bins[p];
        int b = e.x >> 8;
        tmp[lbase[b] + (p - lofs[b])] = e;
    }
}

__global__ __launch_bounds__(256)
void fine_scatter_kernel(const int2* __restrict__ tmp, const int* __restrict__ bucket_ptr,
                         int* __restrict__ row_ptr, int* __restrict__ srcs, int N) {
    __shared__ int hist[256];
    __shared__ int scanb[256];
    __shared__ int cur[256];
    int b = blockIdx.x, t = threadIdx.x;
    int base = bucket_ptr[b];
    int cnt = bucket_ptr[b + 1] - base;
    int n0 = b << 8;
    hist[t] = 0;
    __syncthreads();
    for (int p = t; p < cnt; p += 256)
        atomicAdd(&hist[tmp[base + p].x - n0], 1);
    __syncthreads();
    int c = hist[t];
    scanb[t] = c;
    __syncthreads();
    for (int off = 1; off < 256; off <<= 1) {
        int v = (t >= off) ? scanb[t - off] : 0;
        __syncthreads();
        scanb[t] += v;
        __syncthreads();
    }
    int excl = scanb[t] - c;
    cur[t] = excl;
    if (n0 + t < N) row_ptr[n0 + t] = base + excl;
    __syncthreads();
    for (int p = t; p < cnt; p += 256) {
        int2 e = tmp[base + p];
        int pos = atomicAdd(&cur[e.x - n0], 1);
        srcs[base + pos] = e.y;
    }
}

// ---------------- MFMA GEMM 128: h(fp16) = X @ W^T (+ per-head alphas) ----------------
// Block = 128 rows x 128 cols, 512 threads (8 waves; wave w: rows 16w..16w+15).
// C/D: col=lane&15, row=(lane>>4)*4+reg (verified passing).

__global__ __launch_bounds__(512)
void gemm128_mfma_kernel(const float* __restrict__ X, const float* __restrict__ W,
                         const float* __restrict__ a_src, const float* __restrict__ a_dst,
                         __half* __restrict__ hp, float* __restrict__ asrc,
                         float* __restrict__ adst, int N) {
    __shared__ _Float16 Ah[128][136];
    __shared__ _Float16 Bs[128][136];
    const int t = threadIdx.x;
    const int n0 = blockIdx.x * 128;

#pragma unroll
    for (int i = 0; i < 8; ++i) {
        int lin = t + i * 512;
        int r = lin >> 5;
        int m = lin & 31;
        int gn = n0 + r;
        float4 v = make_float4(0.f, 0.f, 0.f, 0.f);
        if (gn < N) v = *reinterpret_cast<const float4*>(&X[(size_t)gn * 128 + 4 * m]);
        __half2 p0 = __floats2half2_rn(v.x, v.y);
        __half2 p1 = __floats2half2_rn(v.z, v.w);
        uint2 u;
        u.x = *reinterpret_cast<unsigned*>(&p0);
        u.y = *reinterpret_cast<unsigned*>(&p1);
        *reinterpret_cast<uint2*>(&Ah[r][4 * m]) = u;
    }
#pragma unroll
    for (int i = 0; i < 8; ++i) {
        int lin = t + i * 512;
        int n = lin >> 5;
        int m = lin & 31;
        float4 v = *reinterpret_cast<const float4*>(&W[(size_t)n * 128 + 4 * m]);
        __half2 p0 = __floats2half2_rn(v.x, v.y);
        __half2 p1 = __floats2half2_rn(v.z, v.w);
        uint2 u;
        u.x = *reinterpret_cast<unsigned*>(&p0);
        u.y = *reinterpret_cast<unsigned*>(&p1);
        *reinterpret_cast<uint2*>(&Bs[n][4 * m]) = u;
    }
    __syncthreads();

    const int l  = t & 63;
    const int w  = t >> 6;
    const int lr = l & 15;
    const int lg = l >> 4;

    f32x4 acc[8];
#pragma unroll
    for (int tt = 0; tt < 8; ++tt) acc[tt] = (f32x4){0.f, 0.f, 0.f, 0.f};

#pragma unroll
    for (int ks = 0; ks < 4; ++ks) {
        half8 a = *reinterpret_cast<const half8*>(&Ah[16 * w + lr][8 * lg + 32 * ks]);
#pragma unroll
        for (int tt = 0; tt < 8; ++tt) {
            half8 b = *reinterpret_cast<const half8*>(&Bs[16 * tt + lr][8 * lg + 32 * ks]);
            acc[tt] = __builtin_amdgcn_mfma_f32_16x16x32_f16(a, b, acc[tt], 0, 0, 0);
        }
    }

    float av[8], bv[8];
#pragma unroll
    for (int tt = 0; tt < 8; ++tt) {
        av[tt] = a_src[16 * tt + lr];
        bv[tt] = a_dst[16 * tt + lr];
    }
#pragma unroll
    for (int reg = 0; reg < 4; ++reg) {
        int gr = n0 + 16 * w + 4 * lg + reg;
        bool ok = gr < N;
        if (ok) {
#pragma unroll
            for (int tt = 0; tt < 8; ++tt)
                hp[(size_t)gr * 128 + 16 * tt + lr] = __float2half(acc[tt][reg]);
        }
#pragma unroll
        for (int tt = 0; tt < 8; ++tt) {
            float p = acc[tt][reg] * av[tt];
            float q = acc[tt][reg] * bv[tt];
#pragma unroll
            for (int off = 1; off < 16; off <<= 1) {
                p += __shfl_xor(p, off, 16);
                q += __shfl_xor(q, off, 16);
            }
            if (ok && lr == tt) {
                asrc[(size_t)gr * 8 + tt] = p;
                adst[(size_t)gr * 8 + tt] = q;
            }
        }
    }
}

// ---------------- MFMA GEMM 40: h2(fp16) = X @ W2^T (+ single-head alphas) ----------------

__global__ __launch_bounds__(256)
void gemm40_mfma_kernel(const float* __restrict__ X, const float* __restrict__ W,
                        const float* __restrict__ a_src, const float* __restrict__ a_dst,
                        __half* __restrict__ hp, float* __restrict__ asrc,
                        float* __restrict__ adst, int N) {
    __shared__ _Float16 Ah[64][136];
    __shared__ _Float16 Bs[48][136];
    const int t = threadIdx.x;
    const int n0 = blockIdx.x * 64;

#pragma unroll
    for (int i = 0; i < 8; ++i) {
        int lin = t + i * 256;
        int r = lin >> 5;
        int m = lin & 31;
        int gn = n0 + r;
        float4 v = make_float4(0.f, 0.f, 0.f, 0.f);
        if (gn < N) v = *reinterpret_cast<const float4*>(&X[(size_t)gn * 128 + 4 * m]);
        __half2 p0 = __floats2half2_rn(v.x, v.y);
        __half2 p1 = __floats2half2_rn(v.z, v.w);
        uint2 u;
        u.x = *reinterpret_cast<unsigned*>(&p0);
        u.y = *reinterpret_cast<unsigned*>(&p1);
        *reinterpret_cast<uint2*>(&Ah[r][4 * m]) = u;
    }
#pragma unroll
    for (int i = 0; i < 6; ++i) {
        int lin = t + i * 256;
        if (lin < 1536) {
            int n = lin >> 5;
            int m = lin & 31;
            float4 v = make_float4(0.f, 0.f, 0.f, 0.f);
            if (n < 40) v = *reinterpret_cast<const float4*>(&W[(size_t)n * 128 + 4 * m]);
            __half2 p0 = __floats2half2_rn(v.x, v.y);
            __half2 p1 = __floats2half2_rn(v.z, v.w);
            uint2 u;
            u.x = *reinterpret_cast<unsigned*>(&p0);
            u.y = *reinterpret_cast<unsigned*>(&p1);
            *reinterpret_cast<uint2*>(&Bs[n][4 * m]) = u;
        }
    }
    __syncthreads();

    const int l  = t & 63;
    const int w  = t >> 6;
    const int lr = l & 15;
    const int lg = l >> 4;

    f32x4 acc[3];
#pragma unroll
    for (int tt = 0; tt < 3; ++tt) acc[tt] = (f32x4){0.f, 0.f, 0.f, 0.f};

#pragma unroll
    for (int ks = 0; ks < 4; ++ks) {
        half8 a = *reinterpret_cast<const half8*>(&Ah[16 * w + lr][8 * lg + 32 * ks]);
#pragma unroll
        for (int tt = 0; tt < 3; ++tt) {
            half8 b = *reinterpret_cast<const half8*>(&Bs[16 * tt + lr][8 * lg + 32 * ks]);
            acc[tt] = __builtin_amdgcn_mfma_f32_16x16x32_f16(a, b, acc[tt], 0, 0, 0);
        }
    }

    float av[3], bv[3];
#pragma unroll
    for (int tt = 0; tt < 3; ++tt) {
        int j = 16 * tt + lr;
        av[tt] = (j < 40) ? a_src[j] : 0.f;
        bv[tt] = (j < 40) ? a_dst[j] : 0.f;
    }
#pragma unroll
    for (int reg = 0; reg < 4; ++reg) {
        int gr = n0 + 16 * w + 4 * lg + reg;
        bool ok = gr < N;
        float p = 0.f, q = 0.f;
#pragma unroll
        for (int tt = 0; tt < 3; ++tt) {
            int j = 16 * tt + lr;
            if (ok && j < 40) hp[(size_t)gr * 40 + j] = __float2half(acc[tt][reg]);
            p += acc[tt][reg] * av[tt];
            q += acc[tt][reg] * bv[tt];
        }
#pragma unroll
        for (int off = 1; off < 16; off <<= 1) {
            p += __shfl_xor(p, off, 16);
            q += __shfl_xor(q, off, 16);
        }
        if (ok && lr == 0) {
            asrc[gr] = p;
            adst[gr] = q;
        }
    }
}

// ---------------- fused message + softmax, F=128, H=8 ----------------
// 32 lanes per node; two edges in flight (lane bit4 selects edge), 16 lanes/edge,
// uint4 (8 fp16 channels) per lane.  Combine halves with one shfl_xor(16).

__global__ __launch_bounds__(256)
void message128_kernel(const uint4* __restrict__ hh4, const int* __restrict__ row_ptr,
                       const int* __restrict__ srcs,
                       const float* __restrict__ asrc, const float* __restrict__ adst,
                       const float* __restrict__ bias,
                       const float* __restrict__ bn_g, const float* __restrict__ bn_b,
                       const float* __restrict__ bn_m, const float* __restrict__ bn_v,
                       float* __restrict__ out, int N) {
    int node = blockIdx.x * 8 + (threadIdx.x >> 5);
    if (node >= N) return;
    int tc = threadIdx.x & 31;
    int half_id = tc >> 4;
    int cl = tc & 15;
    int hd = cl >> 1;
    int beg = row_ptr[node], end = row_ptr[node + 1];
    float ad = adst[(size_t)node * 8 + hd];
    float ssum = 0.f;
    float acc[8];
#pragma unroll
    for (int q = 0; q < 8; ++q) acc[q] = 0.f;

    int j = beg;
    for (; j + 2 <= end; j += 2) {
        int s = srcs[j + half_id];
        uint4 u = hh4[(size_t)s * 16 + cl];
        float e = asrc[(size_t)s * 8 + hd] + ad;
        e = (e > 0.f) ? e : NEG_SLOPE * e;
        float wgt = __expf(e);
        ssum += wgt;
        float2 f0 = __half22float2(*reinterpret_cast<const __half2*>(&u.x));
        float2 f1 = __half22float2(*reinterpret_cast<const __half2*>(&u.y));
        float2 f2 = __half22float2(*reinterpret_cast<const __half2*>(&u.z));
        float2 f3 = __half22float2(*reinterpret_cast<const __half2*>(&u.w));
        acc[0] += wgt * f0.x; acc[1] += wgt * f0.y;
        acc[2] += wgt * f1.x; acc[3] += wgt * f1.y;
        acc[4] += wgt * f2.x; acc[5] += wgt * f2.y;
        acc[6] += wgt * f3.x; acc[7] += wgt * f3.y;
    }
    if (j < end && half_id == 0) {
        int s = srcs[j];
        uint4 u = hh4[(size_t)s * 16 + cl];
        float e = asrc[(size_t)s * 8 + hd] + ad;
        e = (e > 0.f) ? e : NEG_SLOPE * e;
        float wgt = __expf(e);
        ssum += wgt;
        float2 f0 = __half22float2(*reinterpret_cast<const __half2*>(&u.x));
        float2 f1 = __half22float2(*reinterpret_cast<const __half2*>(&u.y));
        float2 f2 = __half22float2(*reinterpret_cast<const __half2*>(&u.z));
        float2 f3 = __half22float2(*reinterpret_cast<const __half2*>(&u.w));
        acc[0] += wgt * f0.x; acc[1] += wgt * f0.y;
        acc[2] += wgt * f1.x; acc[3] += wgt * f1.y;
        acc[4] += wgt * f2.x; acc[5] += wgt * f2.y;
        acc[6] += wgt * f3.x; acc[7] += wgt * f3.y;
    }
    ssum += __shfl_xor(ssum, 16);
#pragma unroll
    for (int q = 0; q < 8; ++q) acc[q] += __shfl_xor(acc[q], 16);

    if (half_id == 0) {
        float inv = 1.0f / (ssum + 1e-16f);
        int c = cl * 8;
        float r[8];
#pragma unroll
        for (int pp = 0; pp < 2; ++pp) {
            int cc = c + 4 * pp;
            float4 bi = *reinterpret_cast<const float4*>(&bias[cc]);
            float4 g  = *reinterpret_cast<const float4*>(&bn_g[cc]);
            float4 bb = *reinterpret_cast<const float4*>(&bn_b[cc]);
            float4 mm = *reinterpret_cast<const float4*>(&bn_m[cc]);
            float4 vv = *reinterpret_cast<const float4*>(&bn_v[cc]);
            r[4 * pp + 0] = (acc[4 * pp + 0] * inv + bi.x - mm.x) * rsqrtf(vv.x + BN_EPS_C) * g.x + bb.x;
            r[4 * pp + 1] = (acc[4 * pp + 1] * inv + bi.y - mm.y) * rsqrtf(vv.y + BN_EPS_C) * g.y + bb.y;
            r[4 * pp + 2] = (acc[4 * pp + 2] * inv + bi.z - mm.z) * rsqrtf(vv.z + BN_EPS_C) * g.z + bb.z;
            r[4 * pp + 3] = (acc[4 * pp + 3] * inv + bi.w - mm.w) * rsqrtf(vv.w + BN_EPS_C) * g.w + bb.w;
        }
#pragma unroll
        for (int q = 0; q < 8; ++q) r[q] = (r[q] > 0.f) ? r[q] : expm1f(r[q]);
        *reinterpret_cast<float4*>(&out[(size_t)node * 128 + c]) =
            make_float4(r[0], r[1], r[2], r[3]);
        *reinterpret_cast<float4*>(&out[(size_t)node * 128 + c + 4]) =
            make_float4(r[4], r[5], r[6], r[7]);
    }
}

// ---------------- fused message + softmax, F=40, H=1, fp16 gather ----------------

__global__ __launch_bounds__(256)
void message40_kernel(const uint2* __restrict__ hh2, const int* __restrict__ row_ptr,
                      const int* __restrict__ srcs,
                      const float* __restrict__ asrc, const float* __restrict__ adst,
                      const float* __restrict__ b2, float* __restrict__ out, int N) {
    int node = blockIdx.x * 16 + (threadIdx.x >> 4);
    if (node >= N) return;
    int tc = threadIdx.x & 15;
    int beg = row_ptr[node], end = row_ptr[node + 1];
    float ad = adst[node];
    float ssum = 0.f;
    float4 acc = make_float4(0.f, 0.f, 0.f, 0.f);
    int j = beg;
    for (; j + 2 <= end; j += 2) {
        int s0 = srcs[j];
        int s1 = srcs[j + 1];
        uint2 u0 = make_uint2(0u, 0u), u1 = make_uint2(0u, 0u);
        if (tc < 10) {
            u0 = hh2[(size_t)s0 * 10 + tc];
            u1 = hh2[(size_t)s1 * 10 + tc];
        }
        float e0 = asrc[s0] + ad;
        float e1 = asrc[s1] + ad;
        e0 = (e0 > 0.f) ? e0 : NEG_SLOPE * e0;
        e1 = (e1 > 0.f) ? e1 : NEG_SLOPE * e1;
        float w0 = __expf(e0);
        float w1 = __expf(e1);
        ssum += w0 + w1;
        float2 a0 = __half22float2(*reinterpret_cast<const __half2*>(&u0.x));
        float2 b0 = __half22float2(*reinterpret_cast<const __half2*>(&u0.y));
        float2 a1 = __half22float2(*reinterpret_cast<const __half2*>(&u1.x));
        float2 b1 = __half22float2(*reinterpret_cast<const __half2*>(&u1.y));
        acc.x += w0 * a0.x + w1 * a1.x;
        acc.y += w0 * a0.y + w1 * a1.y;
        acc.z += w0 * b0.x + w1 * b1.x;
        acc.w += w0 * b0.y + w1 * b1.y;
    }
    if (j < end) {
        int s0 = srcs[j];
        uint2 u0 = make_uint2(0u, 0u);
        if (tc < 10) u0 = hh2[(size_t)s0 * 10 + tc];
        float e0 = asrc[s0] + ad;
        e0 = (e0 > 0.f) ? e0 : NEG_SLOPE * e0;
        float w0 = __expf(e0);
        ssum += w0;
        float2 a0 = __half22float2(*reinterpret_cast<const __half2*>(&u0.x));
        float2 b0 = __half22float2(*reinterpret_cast<const __half2*>(&u0.y));
        acc.x += w0 * a0.x;
        acc.y += w0 * a0.y;
        acc.z += w0 * b0.x;
        acc.w += w0 * b0.y;
    }
    if (tc < 10) {
        float inv = 1.0f / (ssum + 1e-16f);
        int c = tc * 4;
        float4 bi = *reinterpret_cast<const float4*>(&b2[c]);
        *reinterpret_cast<float4*>(&out[(size_t)node * 40 + c]) =
            make_float4(acc.x * inv + bi.x, acc.y * inv + bi.y,
                        acc.z * inv + bi.z, acc.w * inv + bi.w);
    }
}

// ---------------- launcher ----------------

static inline char* align256(char* p) {
    return (char*)(((uintptr_t)p + 255) & ~(uintptr_t)255);
}

extern "C" void kernel_launch(void* const* d_in, const int* in_sizes, int n_in,
                              void* d_out, int out_size, void* d_ws, size_t ws_size,
                              hipStream_t stream) {
    const float* x   = (const float*)d_in[0];
    const int*   ei  = (const int*)d_in[1];
    const float* W0  = (const float*)d_in[2];
    const float* as0 = (const float*)d_in[3];
    const float* ad0 = (const float*)d_in[4];
    const float* b0  = (const float*)d_in[5];
    const float* g0  = (const float*)d_in[6];
    const float* bb0 = (const float*)d_in[7];
    const float* m0  = (const float*)d_in[8];
    const float* v0  = (const float*)d_in[9];
    const float* W1  = (const float*)d_in[10];
    const float* as1 = (const float*)d_in[11];
    const float* ad1 = (const float*)d_in[12];
    const float* b1  = (const float*)d_in[13];
    const float* g1  = (const float*)d_in[14];
    const float* bb1 = (const float*)d_in[15];
    const float* m1  = (const float*)d_in[16];
    const float* v1  = (const float*)d_in[17];
    const float* W2  = (const float*)d_in[18];
    const float* as2 = (const float*)d_in[19];
    const float* ad2 = (const float*)d_in[20];
    const float* b2  = (const float*)d_in[21];

    const int N  = in_sizes[0] / 128;
    const int E  = in_sizes[1] / 2;
    const int ET = E + N;
    const int NBUK = (N + 255) >> 8;                 // buckets (dst >> 8)
    const int NEB  = (ET + 4095) / 4096;             // edge-chunk blocks

    char* wsp = (char*)d_ws;
    int* bucket_count = (int*)wsp;  wsp = align256(wsp + 256 * 4);
    int* bucket_ptr   = (int*)wsp;  wsp = align256(wsp + 257 * 4);
    int* gcursor      = (int*)wsp;  wsp = align256(wsp + 256 * 4);
    int* row_ptr      = (int*)wsp;  wsp = align256(wsp + (size_t)(N + 1) * 4);
    int2* tmp         = (int2*)wsp; wsp = align256(wsp + (size_t)ET * 8);
    int* srcs         = (int*)wsp;  wsp = align256(wsp + (size_t)ET * 4);
    __half* hh        = (__half*)wsp; wsp = align256(wsp + (size_t)N * 128 * 2);
    __half* h2        = (__half*)wsp; wsp = align256(wsp + (size_t)N * 40 * 2);
    float* feat       = (float*)wsp;  wsp = align256(wsp + (size_t)N * 128 * 4);
    float* asr        = (float*)wsp;  wsp = align256(wsp + (size_t)N * 8 * 4);
    float* adt        = (float*)wsp;  wsp = align256(wsp + (size_t)N * 8 * 4);

    // CSR build (LDS-binned two-level counting sort)
    hipMemsetAsync(bucket_count, 0, 256 * 4, stream);
    bucket_hist_kernel<<<NEB, 256, 0, stream>>>(ei, bucket_count, E, N);
    bucket_scan_kernel<<<1, 256, 0, stream>>>(bucket_count, bucket_ptr, gcursor, row_ptr, N, ET);
    bucket_bin_kernel<<<NEB, 256, 0, stream>>>(ei, gcursor, tmp, E, N);
    fine_scatter_kernel<<<NBUK, 256, 0, stream>>>(tmp, bucket_ptr, row_ptr, srcs, N);

    const int g128 = (N + 127) / 128;
    const int g40  = (N + 63) / 64;

    // layer 0: x -> feat
    gemm128_mfma_kernel<<<g128, 512, 0, stream>>>(x, W0, as0, ad0, hh, asr, adt, N);
    message128_kernel<<<(N + 7) / 8, 256, 0, stream>>>((const uint4*)hh, row_ptr, srcs, asr, adt,
                                                       b0, g0, bb0, m0, v0, feat, N);
    // layer 1: feat -> feat
    gemm128_mfma_kernel<<<g128, 512, 0, stream>>>(feat, W1, as1, ad1, hh, asr, adt, N);
    message128_kernel<<<(N + 7) / 8, 256, 0, stream>>>((const uint4*)hh, row_ptr, srcs, asr, adt,
                                                       b1, g1, bb1, m1, v1, feat, N);
    // layer 2: feat -> d_out
    gemm40_mfma_kernel<<<g40, 256, 0, stream>>>(feat, W2, as2, ad2, h2, asr, adt, N);
    message40_kernel<<<(N + 15) / 16, 256, 0, stream>>>((const uint2*)h2, row_ptr, srcs,
                                                        asr, adt, b2, (float*)d_out, N);
}